// Round 9
// baseline (147.674 us; speedup 1.0000x reference)
//
#include <hip/hip_runtime.h>
#include <math.h>

#define NTOK 2048
#define NBF 266
#define MPAD 272
// zero region: ctx (8*4*266*64 f32) + ksum (8*4*266 f32) + gmax + 12B pad
#define ZWORDS4 138321u   // uint4 count: (2179072 + 34048 + 16) / 16

typedef unsigned short u16;
typedef __attribute__((ext_vector_type(8))) short short8;
typedef __attribute__((ext_vector_type(4))) float f32x4;

__device__ __forceinline__ float bf2f(u16 u) {
  unsigned int x = ((unsigned int)u) << 16;
  return __uint_as_float(x);
}
__device__ __forceinline__ u16 f2bf(float f) {
  unsigned int x = __float_as_uint(f);
  unsigned int r = x + 0x7FFFu + ((x >> 16) & 1u);
  return (u16)(r >> 16);
}
__device__ __forceinline__ float wredsum64(float v) {
  for (int o = 32; o > 0; o >>= 1) v += __shfl_xor(v, o);
  return v;
}
__device__ __forceinline__ float bsum256(float v, float* red) {
  for (int o = 32; o > 0; o >>= 1) v += __shfl_xor(v, o);
  __syncthreads();
  if ((threadIdx.x & 63) == 0) red[threadIdx.x >> 6] = v;
  __syncthreads();
  return red[0] + red[1] + red[2] + red[3];
}
__device__ __forceinline__ float bmax256(float v, float* red) {
  for (int o = 32; o > 0; o >>= 1) v = fmaxf(v, __shfl_xor(v, o));
  __syncthreads();
  if ((threadIdx.x & 63) == 0) red[threadIdx.x >> 6] = v;
  __syncthreads();
  return fmaxf(fmaxf(red[0], red[1]), fmaxf(red[2], red[3]));
}
#define INVF_C 0.4152410118609190f

// ---- prep v3: 128 thr/block, K-split GEMM, LN split, fused ws zeroing ------
__global__ __launch_bounds__(128) void k_prep(
    const int* __restrict__ ids, const float* __restrict__ tok_emb,
    const float* __restrict__ ln1g, const float* __restrict__ ln1b,
    const float* __restrict__ Wk, const float* __restrict__ Wv,
    u16* __restrict__ Kg, u16* __restrict__ Vg, u16* __restrict__ hng,
    float* __restrict__ diagK, float* __restrict__ x0,
    uint4* __restrict__ zbase) {
  int blk = blockIdx.x;            // 8 * 256 blocks
  int b = blk >> 8, nt = blk & 255;
  int n0 = nt * 8;
  int t = threadIdx.x;
  int wv = t >> 6, lane = t & 63;
  __shared__ float hn[8][64];
  __shared__ float idm[8];
  __shared__ float redacc[64 * 65];   // wave1 partial acc, +65 stride

  // fused zeroing of ctx/ksum/gmax (must re-zero every call)
  {
    unsigned int zi = (unsigned int)blk * 128u + (unsigned int)t;
    if (zi < ZWORDS4) zbase[zi] = make_uint4(0u, 0u, 0u, 0u);
  }

  // LN: wave wv handles tokens wv*4 .. wv*4+3
  float g = ln1g[lane], bb = ln1b[lane];
  float invp = exp2f(-INVF_C * (float)(lane & 31));
#pragma unroll
  for (int j2 = 0; j2 < 4; ++j2) {
    int j = wv * 4 + j2;
    int n = n0 + j;
    int id = ids[b * NTOK + n];
    float ang = (float)n * invp;
    float pv = (lane < 32) ? sinf(ang) : cosf(ang);
    float xv = tok_emb[id * 64 + lane] + pv;
    float mu = wredsum64(xv) * 0.015625f;
    float dv = xv - mu;
    float var = wredsum64(dv * dv) * 0.015625f;
    float hv = dv * rsqrtf(var + 1e-5f) * g + bb;
    hn[j][lane] = hv;
    hng[((size_t)b * NTOK + n) * 64 + lane] = f2bf(hv);
    if (lane == 0) idm[j] = (id != 0) ? 1.f : 0.f;
    if (n == 0) x0[b * 64 + lane] = xv;
  }
  __syncthreads();

  // K-split GEMM: wave wv covers d2 in [wv*32, wv*32+32)
  float acc[8][8];
#pragma unroll
  for (int j = 0; j < 8; ++j)
#pragma unroll
    for (int i = 0; i < 8; ++i) acc[j][i] = 0.f;
  const float* wsrc = (lane < 32) ? (Wk + lane * 8) : (Wv + (lane - 32) * 8);
  int dbase = wv * 32;
  for (int d2 = 0; d2 < 32; ++d2) {
    int dd = dbase + d2;
    float4 w0 = *reinterpret_cast<const float4*>(wsrc + dd * 512);
    float4 w1 = *reinterpret_cast<const float4*>(wsrc + dd * 512 + 4);
#pragma unroll
    for (int j = 0; j < 8; ++j) {
      float hv = hn[j][dd];
      acc[j][0] += hv * w0.x; acc[j][1] += hv * w0.y;
      acc[j][2] += hv * w0.z; acc[j][3] += hv * w0.w;
      acc[j][4] += hv * w1.x; acc[j][5] += hv * w1.y;
      acc[j][6] += hv * w1.z; acc[j][7] += hv * w1.w;
    }
  }
  // reduce wave1 partials into wave0
  if (wv == 1) {
#pragma unroll
    for (int j = 0; j < 8; ++j)
#pragma unroll
      for (int i = 0; i < 8; ++i) redacc[lane * 65 + j * 8 + i] = acc[j][i];
  }
  __syncthreads();
  if (wv == 0) {
#pragma unroll
    for (int j = 0; j < 8; ++j)
#pragma unroll
      for (int i = 0; i < 8; ++i) acc[j][i] += redacc[lane * 65 + j * 8 + i];

    if (lane < 32) {              // K-global: rotary, diag, write Kg
      int hh = lane >> 3, db = (lane & 7) * 8;
      float invf[4];
#pragma unroll
      for (int p = 0; p < 4; ++p)
        invf[p] = exp2f(-INVF_C * (float)((db >> 1) + p));
#pragma unroll
      for (int j = 0; j < 8; ++j) {
        int n = n0 + j;
        float kr[8];
#pragma unroll
        for (int p = 0; p < 4; ++p) {
          float ang = (float)n * invf[p];
          float sv = sinf(ang), cv = cosf(ang);
          float e0 = acc[j][2 * p], e1 = acc[j][2 * p + 1];
          kr[2 * p] = e0 * cv - e1 * sv;
          kr[2 * p + 1] = e1 * cv + e0 * sv;
        }
        float dq = 0;
#pragma unroll
        for (int i = 0; i < 8; ++i) dq += kr[i] * kr[i];
        dq += __shfl_xor(dq, 1);
        dq += __shfl_xor(dq, 2);
        dq += __shfl_xor(dq, 4);
        size_t hb = (size_t)(b * 4 + hh) * NTOK + n;
        if ((lane & 7) == 0) diagK[hb] = dq * 0.0625f;
        size_t base = hb * 64 + db;
        ushort4 s0, s1;
        s0.x = f2bf(kr[0]); s0.y = f2bf(kr[1]); s0.z = f2bf(kr[2]); s0.w = f2bf(kr[3]);
        s1.x = f2bf(kr[4]); s1.y = f2bf(kr[5]); s1.z = f2bf(kr[6]); s1.w = f2bf(kr[7]);
        *reinterpret_cast<ushort4*>(Kg + base) = s0;
        *reinterpret_cast<ushort4*>(Kg + base + 4) = s1;
      }
    } else {                      // V-global: mask, write Vg
      int tv = lane - 32;
      int hh = tv >> 3, db = (tv & 7) * 8;
#pragma unroll
      for (int j = 0; j < 8; ++j) {
        int n = n0 + j;
        float maskf = idm[j];
        size_t base = ((size_t)(b * 4 + hh) * NTOK + n) * 64 + db;
        ushort4 m0, m1;
        m0.x = f2bf(acc[j][0] * maskf); m0.y = f2bf(acc[j][1] * maskf);
        m0.z = f2bf(acc[j][2] * maskf); m0.w = f2bf(acc[j][3] * maskf);
        m1.x = f2bf(acc[j][4] * maskf); m1.y = f2bf(acc[j][5] * maskf);
        m1.z = f2bf(acc[j][6] * maskf); m1.w = f2bf(acc[j][7] * maskf);
        *reinterpret_cast<ushort4*>(Vg + base) = m0;
        *reinterpret_cast<ushort4*>(Vg + base + 4) = m1;
      }
    }
  }
}

// ---- stage proj rows [m0, m0+rows) into swizzled bf16 LDS [rows][64] -------
__device__ __forceinline__ void stage_prj(const float* __restrict__ proj,
                                          u16* prjbf, int t, int m0, int rows) {
  for (int c = t; c < rows * 8; c += 256) {
    int r = c >> 3, k0 = (c & 7) * 8;
    int m = m0 + r;
    int e = (r * 64 + k0) ^ ((r & 7) << 3);
    uint4 pk;
    if (m < NBF) {
      const float4* ps = reinterpret_cast<const float4*>(proj + m * 64 + k0);
      float4 p0 = ps[0], p1 = ps[1];
      pk.x = (unsigned)f2bf(p0.x) | ((unsigned)f2bf(p0.y) << 16);
      pk.y = (unsigned)f2bf(p0.z) | ((unsigned)f2bf(p0.w) << 16);
      pk.z = (unsigned)f2bf(p1.x) | ((unsigned)f2bf(p1.y) << 16);
      pk.w = (unsigned)f2bf(p1.z) | ((unsigned)f2bf(p1.w) << 16);
    } else {
      pk.x = pk.y = pk.z = pk.w = 0u;
    }
    *reinterpret_cast<uint4*>(&prjbf[e]) = pk;
  }
}

// ---------------- global max over dash = dn * Kg @ proj^T (MFMA) ------------
__global__ __launch_bounds__(256) void k_max(
    const u16* __restrict__ Kg, const float* __restrict__ proj,
    unsigned int* __restrict__ gmax) {
  int bh = blockIdx.x, ns = blockIdx.y;
  int t = threadIdx.x, lane = t & 63, w = t >> 6;
  __shared__ __align__(16) u16 prjbf[MPAD * 64];
  __shared__ __align__(16) u16 kbf[64 * 64];
  __shared__ float red[4];
  stage_prj(proj, prjbf, t, 0, MPAD);
  float mv = -3e38f;
  int ko = (lane >> 4) * 8;
  for (int c4 = 0; c4 < 2; ++c4) {
    int nb = ns * 128 + c4 * 64;
    __syncthreads();
    for (int p = 0; p < 2; ++p) {
      int idx = t + p * 256;
      int n = idx >> 3, k0 = (idx & 7) * 8;
      uint4 src = *reinterpret_cast<const uint4*>(
          Kg + ((size_t)bh * NTOK + nb + n) * 64 + k0);
      *reinterpret_cast<uint4*>(&kbf[(n * 64 + k0) ^ ((n & 7) << 3)]) = src;
    }
    __syncthreads();
    int nl = w * 16 + (lane & 15);
    short8 a0 = *reinterpret_cast<const short8*>(&kbf[(nl * 64 + ko) ^ ((nl & 7) << 3)]);
    short8 a1 = *reinterpret_cast<const short8*>(&kbf[(nl * 64 + ko + 32) ^ ((nl & 7) << 3)]);
#pragma unroll
    for (int mt = 0; mt < 17; ++mt) {
      int m = mt * 16 + (lane & 15);
      short8 b0 = *reinterpret_cast<const short8*>(&prjbf[(m * 64 + ko) ^ ((m & 7) << 3)]);
      short8 b1 = *reinterpret_cast<const short8*>(&prjbf[(m * 64 + ko + 32) ^ ((m & 7) << 3)]);
      f32x4 d = {0.f, 0.f, 0.f, 0.f};
      d = __builtin_amdgcn_mfma_f32_16x16x32_bf16(a0, b0, d, 0, 0, 0);
      d = __builtin_amdgcn_mfma_f32_16x16x32_bf16(a1, b1, d, 0, 0, 0);
      if (m < NBF) {
        mv = fmaxf(mv, fmaxf(fmaxf(d[0], d[1]), fmaxf(d[2], d[3])));
      }
    }
  }
  mv *= 0.35355339059327373f;
  for (int o = 32; o > 0; o >>= 1) mv = fmaxf(mv, __shfl_xor(mv, o));
  __syncthreads();
  if (lane == 0) red[w] = mv;
  __syncthreads();
  if (t == 0) {
    float m2 = fmaxf(fmaxf(red[0], red[1]), fmaxf(red[2], red[3]));
    unsigned int b = __float_as_uint(m2);
    unsigned int u = (b & 0x80000000u) ? ~b : (b | 0x80000000u);
    atomicMax(gmax, u);
  }
}

// ---------------- ctx = kp^T @ Vg, ksum = sum_n kp (MFMA) -------------------
__global__ __launch_bounds__(256) void k_ctx(
    const u16* __restrict__ Kg, const u16* __restrict__ Vg,
    const float* __restrict__ diagK, const float* __restrict__ proj,
    const unsigned int* __restrict__ gmax,
    float* __restrict__ ctx, float* __restrict__ ksum) {
  int bh = blockIdx.x, ns = blockIdx.y, mz = blockIdx.z;
  int m0 = mz * 144;
  int nmt = mz ? 8 : 9;
  int t = threadIdx.x, lane = t & 63, w = t >> 6;
  __shared__ __align__(16) u16 prjbf[144 * 64];
  __shared__ __align__(16) u16 kpT[144 * 64];
  __shared__ __align__(16) u16 kbf[64 * 64];
  __shared__ __align__(16) u16 vbT[64 * 64];
  __shared__ float dg[64];
  __shared__ float ksl[144];
  stage_prj(proj, prjbf, t, m0, 144);
  if (t < 144) ksl[t] = 0.f;
  unsigned int u = *gmax;
  unsigned int bb = (u & 0x80000000u) ? (u & 0x7FFFFFFFu) : ~u;
  float mx = __uint_as_float(bb);
  const float dn = 0.35355339059327373f;
  const float ratio = 1.0f / sqrtf(266.0f);
  int ko = (lane >> 4) * 8;
  f32x4 acc[9];
  float ksacc[9];
#pragma unroll
  for (int i = 0; i < 9; ++i) { acc[i] = (f32x4){0.f, 0.f, 0.f, 0.f}; ksacc[i] = 0.f; }

  for (int c4 = 0; c4 < 4; ++c4) {
    int nb = ns * 256 + c4 * 64;
    for (int p = 0; p < 2; ++p) {
      int idx = t + p * 256;
      int n = idx >> 3, k0 = (idx & 7) * 8;
      uint4 src = *reinterpret_cast<const uint4*>(
          Kg + ((size_t)bh * NTOK + nb + n) * 64 + k0);
      *reinterpret_cast<uint4*>(&kbf[(n * 64 + k0) ^ ((n & 7) << 3)]) = src;
      uint4 vv = *reinterpret_cast<const uint4*>(
          Vg + ((size_t)bh * NTOK + nb + n) * 64 + k0);
      u16 pv[8];
      *reinterpret_cast<uint4*>(pv) = vv;
#pragma unroll
      for (int i = 0; i < 8; ++i) {
        int d = k0 + i;
        vbT[(d * 64 + n) ^ ((d & 7) << 3)] = pv[i];
      }
    }
    if (t < 64) dg[t] = diagK[(size_t)bh * NTOK + nb + t];
    __syncthreads();
    {
      int nl = w * 16 + (lane & 15);
      short8 a0 = *reinterpret_cast<const short8*>(&kbf[(nl * 64 + ko) ^ ((nl & 7) << 3)]);
      short8 a1 = *reinterpret_cast<const short8*>(&kbf[(nl * 64 + ko + 32) ^ ((nl & 7) << 3)]);
      float dgv[4];
#pragma unroll
      for (int r = 0; r < 4; ++r) dgv[r] = dg[w * 16 + (lane >> 4) * 4 + r];
      int n0 = w * 16 + (lane >> 4) * 4;
#pragma unroll
      for (int mt = 0; mt < 9; ++mt) {
        if (mt < nmt) {
          int lr = mt * 16 + (lane & 15);
          short8 b0 = *reinterpret_cast<const short8*>(&prjbf[(lr * 64 + ko) ^ ((lr & 7) << 3)]);
          short8 b1 = *reinterpret_cast<const short8*>(&prjbf[(lr * 64 + ko + 32) ^ ((lr & 7) << 3)]);
          f32x4 d = {0.f, 0.f, 0.f, 0.f};
          d = __builtin_amdgcn_mfma_f32_16x16x32_bf16(a0, b0, d, 0, 0, 0);
          d = __builtin_amdgcn_mfma_f32_16x16x32_bf16(a1, b1, d, 0, 0, 0);
          float kp0 = ratio * (expf(dn * d[0] - dgv[0] - mx) + 1e-4f);
          float kp1 = ratio * (expf(dn * d[1] - dgv[1] - mx) + 1e-4f);
          float kp2 = ratio * (expf(dn * d[2] - dgv[2] - mx) + 1e-4f);
          float kp3 = ratio * (expf(dn * d[3] - dgv[3] - mx) + 1e-4f);
          ushort4 pkk;
          pkk.x = f2bf(kp0); pkk.y = f2bf(kp1); pkk.z = f2bf(kp2); pkk.w = f2bf(kp3);
          *reinterpret_cast<ushort4*>(&kpT[(lr * 64 + n0) ^ ((lr & 7) << 3)]) = pkk;
          float ksp = kp0 + kp1 + kp2 + kp3;
          ksp += __shfl_xor(ksp, 16);
          ksp += __shfl_xor(ksp, 32);
          ksacc[mt] += ksp;
        }
      }
    }
    __syncthreads();
    {
      int dcol = w * 16 + (lane & 15);
      short8 vb0 = *reinterpret_cast<const short8*>(&vbT[(dcol * 64 + ko) ^ ((dcol & 7) << 3)]);
      short8 vb1 = *reinterpret_cast<const short8*>(&vbT[(dcol * 64 + ko + 32) ^ ((dcol & 7) << 3)]);
#pragma unroll
      for (int mt = 0; mt < 9; ++mt) {
        if (mt < nmt) {
          int lr = mt * 16 + (lane & 15);
          short8 a0 = *reinterpret_cast<const short8*>(&kpT[(lr * 64 + ko) ^ ((lr & 7) << 3)]);
          short8 a1 = *reinterpret_cast<const short8*>(&kpT[(lr * 64 + ko + 32) ^ ((lr & 7) << 3)]);
          acc[mt] = __builtin_amdgcn_mfma_f32_16x16x32_bf16(a0, vb0, acc[mt], 0, 0, 0);
          acc[mt] = __builtin_amdgcn_mfma_f32_16x16x32_bf16(a1, vb1, acc[mt], 0, 0, 0);
        }
      }
    }
    __syncthreads();
  }
  int dcol = w * 16 + (lane & 15);
#pragma unroll
  for (int mt = 0; mt < 9; ++mt) {
    if (mt < nmt) {
#pragma unroll
      for (int r = 0; r < 4; ++r) {
        int m = m0 + mt * 16 + (lane >> 4) * 4 + r;
        if (m < NBF)
          atomicAdd(&ctx[((size_t)bh * NBF + m) * 64 + dcol], acc[mt][r]);
      }
      if (lane < 16) atomicAdd(&ksl[mt * 16 + lane], ksacc[mt]);
    }
  }
  __syncthreads();
  if (t < 144 && m0 + t < NBF)
    atomicAdd(&ksum[(size_t)bh * NBF + m0 + t], ksl[t]);
}

// ---------------- attention row 0, one block per (b, head) ------------------
__global__ __launch_bounds__(256) void k_att(
    const int* __restrict__ ids,
    const float* __restrict__ ln1g, const float* __restrict__ ln1b,
    const float* __restrict__ Wq, const float* __restrict__ Wk,
    const float* __restrict__ Wv, const float* __restrict__ proj,
    const u16* __restrict__ hng,
    const float* __restrict__ ctx, const float* __restrict__ ksum,
    const float* __restrict__ x0, float* __restrict__ att) {
  int b = blockIdx.x, h = blockIdx.y;
  int t = threadIdx.x;
  int lane = t & 63, wg = t >> 6;
  __shared__ float hn1[64], qh[64], qpart[4][64], red[4], pol[4][64];
  __shared__ float buf[272];
  __shared__ float dots[2048];
  __shared__ float wkq[64], svec[64];
  __shared__ u16 vst[512 * 64];
  const float dn = 0.35355339059327373f;
  const float ratio = 1.0f / sqrtf(266.0f);

  if (t < 64) {
    float xv = x0[b * 64 + t];
    float mu = wredsum64(xv) * 0.015625f;
    float dv = xv - mu;
    float var = wredsum64(dv * dv) * 0.015625f;
    hn1[t] = dv * rsqrtf(var + 1e-5f) * ln1g[t] + ln1b[t];
  }
  __syncthreads();
  {
    float p = 0;
#pragma unroll
    for (int dd = 0; dd < 16; ++dd)
      p += hn1[wg * 16 + dd] * Wq[(wg * 16 + dd) * 512 + h * 64 + lane];
    qpart[wg][lane] = p;
  }
  __syncthreads();
  if (t < 64) qh[t] = qpart[0][t] + qpart[1][t] + qpart[2][t] + qpart[3][t];
  __syncthreads();

  if (h < 4) {
    int bh = b * 4 + h;
    float dq = 0;
#pragma unroll
    for (int d = 0; d < 64; ++d) dq += qh[d] * qh[d];
    dq *= 0.0625f;
    float lmax = -3e38f;
#pragma unroll
    for (int pass = 0; pass < 2; ++pass) {
      int m = t + pass * 256;
      if (m < NBF) {
        const float4* pp = reinterpret_cast<const float4*>(proj + m * 64);
        float s = 0;
#pragma unroll
        for (int q4 = 0; q4 < 16; ++q4) {
          float4 uu = pp[q4];
          s += qh[q4 * 4] * uu.x + qh[q4 * 4 + 1] * uu.y +
               qh[q4 * 4 + 2] * uu.z + qh[q4 * 4 + 3] * uu.w;
        }
        float dash = dn * s;
        buf[m] = dash;
        lmax = fmaxf(lmax, dash);
      }
    }
    float mxq = bmax256(lmax, red);
    float part = 0;
#pragma unroll
    for (int pass = 0; pass < 2; ++pass) {
      int m = t + pass * 256;
      if (m < NBF) {
        float qp = ratio * (expf(buf[m] - dq - mxq) + 1e-4f);
        buf[m] = qp;
        part += qp * ksum[(size_t)bh * NBF + m];
      }
    }
    float den = bsum256(part, red);
    __syncthreads();
    {
      float s = 0;
      for (int m = wg; m < NBF; m += 4)
        s += buf[m] * ctx[((size_t)bh * NBF + m) * 64 + lane];
      pol[wg][lane] = s;
    }
    __syncthreads();
    if (t < 64)
      att[b * 512 + h * 64 + t] =
          (pol[0][t] + pol[1][t] + pol[2][t] + pol[3][t]) / den;
  } else {
    int ch = h * 64;
    if (t < 64) {
      float s = 0;
#pragma unroll 8
      for (int j = 0; j < 64; ++j) s += Wk[t * 512 + ch + j] * qh[j];
      wkq[t] = s;
    }
    __syncthreads();
    const u16* hnb = hng + (size_t)b * NTOK * 64;
    float lmax = -3e38f;
#pragma unroll
    for (int i = 0; i < 8; ++i) {
      int n1 = t + i * 256;
      const ushort4* hr = reinterpret_cast<const ushort4*>(hnb + (size_t)n1 * 64);
      float s = 0;
#pragma unroll
      for (int d4 = 0; d4 < 16; ++d4) {
        ushort4 uu = hr[d4];
        s += wkq[d4 * 4] * bf2f(uu.x) + wkq[d4 * 4 + 1] * bf2f(uu.y) +
             wkq[d4 * 4 + 2] * bf2f(uu.z) + wkq[d4 * 4 + 3] * bf2f(uu.w);
      }
      float dv = s * 0.125f;
      if (ids[b * NTOK + n1] == 0) dv = -1e9f;
      dots[n1] = dv;
      lmax = fmaxf(lmax, dv);
    }
    float mxl = bmax256(lmax, red);
    float ps = 0;
#pragma unroll
    for (int i = 0; i < 8; ++i) {
      int n1 = t + i * 256;
      float p = expf(dots[n1] - mxl);
      dots[n1] = p;
      ps += p;
    }
    float sden = bsum256(ps, red);
    float acc = 0;
    for (int c = 0; c < 4; ++c) {
      __syncthreads();
      const ushort4* src = reinterpret_cast<const ushort4*>(hnb + (size_t)(c * 512) * 64);
      ushort4* dst = reinterpret_cast<ushort4*>(vst);
#pragma unroll
      for (int i = 0; i < 32; ++i) dst[t + i * 256] = src[t + i * 256];
      __syncthreads();
      int r0 = wg * 128;
#pragma unroll 8
      for (int r = 0; r < 128; ++r)
        acc += dots[c * 512 + r0 + r] * bf2f(vst[(r0 + r) * 64 + lane]);
    }
    __syncthreads();
    pol[wg][lane] = acc;
    __syncthreads();
    if (t < 64) svec[t] = pol[0][t] + pol[1][t] + pol[2][t] + pol[3][t];
    __syncthreads();
    {
      float p2 = 0;
#pragma unroll
      for (int dd = 0; dd < 16; ++dd)
        p2 += svec[wg * 16 + dd] * Wv[(wg * 16 + dd) * 512 + ch + lane];
      pol[wg][lane] = p2;
    }
    __syncthreads();
    if (t < 64)
      att[b * 512 + h * 64 + t] =
          (pol[0][t] + pol[1][t] + pol[2][t] + pol[3][t]) / sden;
  }
}

// ---------------- tail at position 0: Wo, FF, final LN, heads ----------------
__global__ __launch_bounds__(256) void k_fin2(
    const float* __restrict__ ln2g, const float* __restrict__ ln2b,
    const float* __restrict__ Wo,
    const float* __restrict__ W1, const float* __restrict__ b1,
    const float* __restrict__ W2, const float* __restrict__ b2,
    const float* __restrict__ lnfg, const float* __restrict__ lnfb,
    const float* __restrict__ Wout, const float* __restrict__ bout,
    const float* __restrict__ Wc1, const float* __restrict__ bc1,
    const float* __restrict__ Wc2, const float* __restrict__ bc2,
    const float* __restrict__ x0, const float* __restrict__ att,
    float* __restrict__ out) {
  int b = blockIdx.x;
  int t = threadIdx.x;
  int lane = t & 63, wg = t >> 6;
  __shared__ float o512s[512], x0s[64], part[4][64];
  __shared__ float y1[64], hn2[64], gact[256], hfin[64], repS[64], c1s[32];
  o512s[t] = att[b * 512 + t];
  o512s[t + 256] = att[b * 512 + t + 256];
  if (t < 64) x0s[t] = x0[b * 64 + t];
  __syncthreads();
  {
    float s = 0;
#pragma unroll 4
    for (int c = wg * 128; c < wg * 128 + 128; ++c) s += o512s[c] * Wo[c * 64 + lane];
    part[wg][lane] = s;
  }
  __syncthreads();
  if (t < 64) {
    float yv = x0s[t] + part[0][t] + part[1][t] + part[2][t] + part[3][t];
    y1[t] = yv;
    float mu = wredsum64(yv) * 0.015625f;
    float dv = yv - mu;
    float var = wredsum64(dv * dv) * 0.015625f;
    hn2[t] = dv * rsqrtf(var + 1e-5f) * ln2g[t] + ln2b[t];
  }
  __syncthreads();
  {
    float s = b1[t];
#pragma unroll 4
    for (int d = 0; d < 64; ++d) s += hn2[d] * W1[d * 256 + t];
    gact[t] = 0.5f * s * (1.f + erff(s * 0.7071067811865475f));
  }
  __syncthreads();
  {
    float s = 0;
#pragma unroll 4
    for (int j = wg * 64; j < wg * 64 + 64; ++j) s += gact[j] * W2[j * 64 + lane];
    part[wg][lane] = s;
  }
  __syncthreads();
  if (t < 64) {
    float y2 = x0s[t] + b2[t] + part[0][t] + part[1][t] + part[2][t] + part[3][t];
    float hm = 0.5f * (y1[t] + y2);
    float mu = wredsum64(hm) * 0.015625f;
    float dv = hm - mu;
    float var = wredsum64(dv * dv) * 0.015625f;
    hfin[t] = dv * rsqrtf(var + 1e-5f) * lnfg[t] + lnfb[t];
  }
  __syncthreads();
  {
    float s = 0;
#pragma unroll
    for (int dd = 0; dd < 16; ++dd)
      s += hfin[wg * 16 + dd] * Wout[(wg * 16 + dd) * 64 + lane];
    part[wg][lane] = s;
  }
  __syncthreads();
  if (t < 64) {
    float s = bout[t] + part[0][t] + part[1][t] + part[2][t] + part[3][t];
    repS[t] = s;
    out[16 + b * 64 + t] = s;
  }
  __syncthreads();
  if (t < 32) {
    float s = bc1[t];
#pragma unroll 4
    for (int d = 0; d < 64; ++d) s += repS[d] * Wc1[d * 32 + t];
    c1s[t] = fmaxf(s, 0.f);
  }
  __syncthreads();
  if (t < 2) {
    float s = bc2[t];
#pragma unroll
    for (int jj = 0; jj < 32; ++jj) s += c1s[jj] * Wc2[jj * 2 + t];
    out[b * 2 + t] = s;
  }
}

extern "C" void kernel_launch(void* const* d_in, const int* in_sizes, int n_in,
                              void* d_out, int out_size, void* d_ws, size_t ws_size,
                              hipStream_t stream) {
  (void)in_sizes; (void)n_in; (void)out_size; (void)ws_size;
  const int* ids = (const int*)d_in[0];
  const float* tok = (const float*)d_in[1];
  const float* ln1g = (const float*)d_in[2];
  const float* ln1b = (const float*)d_in[3];
  const float* Wq = (const float*)d_in[4];
  const float* Wk = (const float*)d_in[5];
  const float* Wv = (const float*)d_in[6];
  const float* Wo = (const float*)d_in[7];
  const float* ln2g = (const float*)d_in[8];
  const float* ln2b = (const float*)d_in[9];
  const float* W1 = (const float*)d_in[10];
  const float* b1 = (const float*)d_in[11];
  const float* W2 = (const float*)d_in[12];
  const float* b2 = (const float*)d_in[13];
  const float* lnfg = (const float*)d_in[14];
  const float* lnfb = (const float*)d_in[15];
  const float* Wout = (const float*)d_in[16];
  const float* bout = (const float*)d_in[17];
  const float* Wc1 = (const float*)d_in[18];
  const float* bc1 = (const float*)d_in[19];
  const float* Wc2 = (const float*)d_in[20];
  const float* bc2 = (const float*)d_in[21];
  const float* proj = (const float*)d_in[22];

  uint8_t* w = (uint8_t*)d_ws;
  size_t off = 0;
  const size_t big = (size_t)8 * 4 * NTOK * 64 * 2;  // 4.19 MB each
  u16* Kg = (u16*)(w + off); off += big;
  u16* Vg = (u16*)(w + off); off += big;
  u16* hng = (u16*)(w + off); off += (size_t)8 * NTOK * 64 * 2;  // 2 MB
  float* diagK = (float*)(w + off); off += (size_t)8 * 4 * NTOK * 4;
  float* ctx = (float*)(w + off); off += (size_t)8 * 4 * NBF * 64 * 4;
  float* ksum = (float*)(w + off); off += (size_t)8 * 4 * NBF * 4;
  unsigned int* gmax = (unsigned int*)(w + off); off += 4;
  off += 12;  // pad so the zero region (ctx..gmax) is a whole uint4 count
  float* x0 = (float*)(w + off); off += 64 * 8 * 4;
  float* att = (float*)(w + off); off += (size_t)8 * 512 * 4;

  k_prep<<<8 * 256, 128, 0, stream>>>(ids, tok, ln1g, ln1b, Wk, Wv, Kg, Vg, hng,
                                      diagK, x0, (uint4*)ctx);
  k_max<<<dim3(32, 16), 256, 0, stream>>>(Kg, proj, gmax);
  k_ctx<<<dim3(32, 8, 2), 256, 0, stream>>>(Kg, Vg, diagK, proj, gmax, ctx, ksum);
  k_att<<<dim3(8, 8), 256, 0, stream>>>(ids, ln1g, ln1b, Wq, Wk, Wv, proj, hng,
                                        ctx, ksum, x0, att);
  k_fin2<<<8, 256, 0, stream>>>(ln2g, ln2b, Wo, W1, b1, W2, b2, lnfg, lnfb, Wout,
                                bout, Wc1, bc1, Wc2, bc2, x0, att, (float*)d_out);
}

// Round 10
// 140.652 us; speedup vs baseline: 1.0499x; 1.0499x over previous
//
#include <hip/hip_runtime.h>
#include <math.h>

#define NTOK 2048
#define NBF 266
#define MPAD 272
// zero region: ctx (8*4*266*64 f32) + ksum (8*4*266 f32) + gmax + 12B pad
#define ZWORDS4 138321u   // uint4 count: (2179072 + 34048 + 16) / 16

typedef unsigned short u16;
typedef __attribute__((ext_vector_type(8))) short short8;
typedef __attribute__((ext_vector_type(4))) float f32x4;

__device__ __forceinline__ float bf2f(u16 u) {
  unsigned int x = ((unsigned int)u) << 16;
  return __uint_as_float(x);
}
__device__ __forceinline__ u16 f2bf(float f) {
  unsigned int x = __float_as_uint(f);
  unsigned int r = x + 0x7FFFu + ((x >> 16) & 1u);
  return (u16)(r >> 16);
}
__device__ __forceinline__ float wredsum64(float v) {
  for (int o = 32; o > 0; o >>= 1) v += __shfl_xor(v, o);
  return v;
}
__device__ __forceinline__ float bsum256(float v, float* red) {
  for (int o = 32; o > 0; o >>= 1) v += __shfl_xor(v, o);
  __syncthreads();
  if ((threadIdx.x & 63) == 0) red[threadIdx.x >> 6] = v;
  __syncthreads();
  return red[0] + red[1] + red[2] + red[3];
}
__device__ __forceinline__ float bmax256(float v, float* red) {
  for (int o = 32; o > 0; o >>= 1) v = fmaxf(v, __shfl_xor(v, o));
  __syncthreads();
  if ((threadIdx.x & 63) == 0) red[threadIdx.x >> 6] = v;
  __syncthreads();
  return fmaxf(fmaxf(red[0], red[1]), fmaxf(red[2], red[3]));
}
#define INVF_C 0.4152410118609190f

// ---- prep: 64 thr / 8 tokens; launch_bounds(64,2) -> 256-VGPR cap, NO SPILL
__global__ __launch_bounds__(64, 2) void k_prep(
    const int* __restrict__ ids, const float* __restrict__ tok_emb,
    const float* __restrict__ ln1g, const float* __restrict__ ln1b,
    const float* __restrict__ Wk, const float* __restrict__ Wv,
    u16* __restrict__ Kg, u16* __restrict__ Vg, u16* __restrict__ hng,
    float* __restrict__ diagK, float* __restrict__ x0,
    uint4* __restrict__ zbase) {
  int blk = blockIdx.x;            // 8 * 256 blocks
  int b = blk >> 8, nt = blk & 255;
  int n0 = nt * 8;
  int t = threadIdx.x;
  __shared__ float hn[8][64];
  int idv[8];

  // fused zeroing of ctx/ksum/gmax (must re-zero every call): 2 words/thread
#pragma unroll
  for (int p = 0; p < 2; ++p) {
    unsigned int zi = (unsigned int)blk * 128u + (unsigned int)(p * 64 + t);
    if (zi < ZWORDS4) zbase[zi] = make_uint4(0u, 0u, 0u, 0u);
  }

  float g = ln1g[t], bb = ln1b[t];
  float invp = exp2f(-INVF_C * (float)(t & 31));
#pragma unroll
  for (int j = 0; j < 8; ++j) {
    int n = n0 + j;
    int id = ids[b * NTOK + n];
    idv[j] = id;
    float ang = (float)n * invp;
    float pv = (t < 32) ? sinf(ang) : cosf(ang);
    float xv = tok_emb[id * 64 + t] + pv;
    float mu = wredsum64(xv) * 0.015625f;
    float dv = xv - mu;
    float var = wredsum64(dv * dv) * 0.015625f;
    float hv = dv * rsqrtf(var + 1e-5f) * g + bb;
    hn[j][t] = hv;
    hng[((size_t)b * NTOK + n) * 64 + t] = f2bf(hv);
    if (n == 0) x0[b * 64 + t] = xv;
  }
  __syncthreads();

  // global-head columns only: Wk[:,0:256] (t<32) or Wv[:,0:256] (t>=32)
  float acc[8][8];
#pragma unroll
  for (int j = 0; j < 8; ++j)
#pragma unroll
    for (int i = 0; i < 8; ++i) acc[j][i] = 0.f;
  const float* wsrc = (t < 32) ? (Wk + t * 8) : (Wv + (t - 32) * 8);
  for (int d2 = 0; d2 < 64; ++d2) {
    float4 w0 = *reinterpret_cast<const float4*>(wsrc + d2 * 512);
    float4 w1 = *reinterpret_cast<const float4*>(wsrc + d2 * 512 + 4);
#pragma unroll
    for (int j = 0; j < 8; ++j) {
      float hv = hn[j][d2];
      acc[j][0] += hv * w0.x; acc[j][1] += hv * w0.y;
      acc[j][2] += hv * w0.z; acc[j][3] += hv * w0.w;
      acc[j][4] += hv * w1.x; acc[j][5] += hv * w1.y;
      acc[j][6] += hv * w1.z; acc[j][7] += hv * w1.w;
    }
  }

  if (t < 32) {                   // K-global: rotary, diag, write Kg
    int hh = t >> 3, db = (t & 7) * 8;
    float invf[4];
#pragma unroll
    for (int p = 0; p < 4; ++p)
      invf[p] = exp2f(-INVF_C * (float)((db >> 1) + p));
#pragma unroll
    for (int j = 0; j < 8; ++j) {
      int n = n0 + j;
      float kr[8];
#pragma unroll
      for (int p = 0; p < 4; ++p) {
        float ang = (float)n * invf[p];
        float sv = sinf(ang), cv = cosf(ang);
        float e0 = acc[j][2 * p], e1 = acc[j][2 * p + 1];
        kr[2 * p] = e0 * cv - e1 * sv;
        kr[2 * p + 1] = e1 * cv + e0 * sv;
      }
      float dq = 0;
#pragma unroll
      for (int i = 0; i < 8; ++i) dq += kr[i] * kr[i];
      dq += __shfl_xor(dq, 1);
      dq += __shfl_xor(dq, 2);
      dq += __shfl_xor(dq, 4);
      size_t hb = (size_t)(b * 4 + hh) * NTOK + n;
      if ((t & 7) == 0) diagK[hb] = dq * 0.0625f;
      size_t base = hb * 64 + db;
      ushort4 s0, s1;
      s0.x = f2bf(kr[0]); s0.y = f2bf(kr[1]); s0.z = f2bf(kr[2]); s0.w = f2bf(kr[3]);
      s1.x = f2bf(kr[4]); s1.y = f2bf(kr[5]); s1.z = f2bf(kr[6]); s1.w = f2bf(kr[7]);
      *reinterpret_cast<ushort4*>(Kg + base) = s0;
      *reinterpret_cast<ushort4*>(Kg + base + 4) = s1;
    }
  } else {                        // V-global: mask, write Vg
    int tv = t - 32;
    int hh = tv >> 3, db = (tv & 7) * 8;
#pragma unroll
    for (int j = 0; j < 8; ++j) {
      int n = n0 + j;
      float maskf = (idv[j] != 0) ? 1.f : 0.f;
      size_t base = ((size_t)(b * 4 + hh) * NTOK + n) * 64 + db;
      ushort4 m0, m1;
      m0.x = f2bf(acc[j][0] * maskf); m0.y = f2bf(acc[j][1] * maskf);
      m0.z = f2bf(acc[j][2] * maskf); m0.w = f2bf(acc[j][3] * maskf);
      m1.x = f2bf(acc[j][4] * maskf); m1.y = f2bf(acc[j][5] * maskf);
      m1.z = f2bf(acc[j][6] * maskf); m1.w = f2bf(acc[j][7] * maskf);
      *reinterpret_cast<ushort4*>(Vg + base) = m0;
      *reinterpret_cast<ushort4*>(Vg + base + 4) = m1;
    }
  }
}

// ---- stage proj rows [m0, m0+rows) into swizzled bf16 LDS [rows][64] -------
__device__ __forceinline__ void stage_prj(const float* __restrict__ proj,
                                          u16* prjbf, int t, int m0, int rows) {
  for (int c = t; c < rows * 8; c += 256) {
    int r = c >> 3, k0 = (c & 7) * 8;
    int m = m0 + r;
    int e = (r * 64 + k0) ^ ((r & 7) << 3);
    uint4 pk;
    if (m < NBF) {
      const float4* ps = reinterpret_cast<const float4*>(proj + m * 64 + k0);
      float4 p0 = ps[0], p1 = ps[1];
      pk.x = (unsigned)f2bf(p0.x) | ((unsigned)f2bf(p0.y) << 16);
      pk.y = (unsigned)f2bf(p0.z) | ((unsigned)f2bf(p0.w) << 16);
      pk.z = (unsigned)f2bf(p1.x) | ((unsigned)f2bf(p1.y) << 16);
      pk.w = (unsigned)f2bf(p1.z) | ((unsigned)f2bf(p1.w) << 16);
    } else {
      pk.x = pk.y = pk.z = pk.w = 0u;
    }
    *reinterpret_cast<uint4*>(&prjbf[e]) = pk;
  }
}

// ---------------- global max over dash = dn * Kg @ proj^T (MFMA) ------------
__global__ __launch_bounds__(256) void k_max(
    const u16* __restrict__ Kg, const float* __restrict__ proj,
    unsigned int* __restrict__ gmax) {
  int bh = blockIdx.x, ns = blockIdx.y;
  int t = threadIdx.x, lane = t & 63, w = t >> 6;
  __shared__ __align__(16) u16 prjbf[MPAD * 64];
  __shared__ __align__(16) u16 kbf[64 * 64];
  __shared__ float red[4];
  stage_prj(proj, prjbf, t, 0, MPAD);
  float mv = -3e38f;
  int ko = (lane >> 4) * 8;
  for (int c4 = 0; c4 < 2; ++c4) {
    int nb = ns * 128 + c4 * 64;
    __syncthreads();
    for (int p = 0; p < 2; ++p) {
      int idx = t + p * 256;
      int n = idx >> 3, k0 = (idx & 7) * 8;
      uint4 src = *reinterpret_cast<const uint4*>(
          Kg + ((size_t)bh * NTOK + nb + n) * 64 + k0);
      *reinterpret_cast<uint4*>(&kbf[(n * 64 + k0) ^ ((n & 7) << 3)]) = src;
    }
    __syncthreads();
    int nl = w * 16 + (lane & 15);
    short8 a0 = *reinterpret_cast<const short8*>(&kbf[(nl * 64 + ko) ^ ((nl & 7) << 3)]);
    short8 a1 = *reinterpret_cast<const short8*>(&kbf[(nl * 64 + ko + 32) ^ ((nl & 7) << 3)]);
#pragma unroll
    for (int mt = 0; mt < 17; ++mt) {
      int m = mt * 16 + (lane & 15);
      short8 b0 = *reinterpret_cast<const short8*>(&prjbf[(m * 64 + ko) ^ ((m & 7) << 3)]);
      short8 b1 = *reinterpret_cast<const short8*>(&prjbf[(m * 64 + ko + 32) ^ ((m & 7) << 3)]);
      f32x4 d = {0.f, 0.f, 0.f, 0.f};
      d = __builtin_amdgcn_mfma_f32_16x16x32_bf16(a0, b0, d, 0, 0, 0);
      d = __builtin_amdgcn_mfma_f32_16x16x32_bf16(a1, b1, d, 0, 0, 0);
      if (m < NBF) {
        mv = fmaxf(mv, fmaxf(fmaxf(d[0], d[1]), fmaxf(d[2], d[3])));
      }
    }
  }
  mv *= 0.35355339059327373f;
  for (int o = 32; o > 0; o >>= 1) mv = fmaxf(mv, __shfl_xor(mv, o));
  __syncthreads();
  if (lane == 0) red[w] = mv;
  __syncthreads();
  if (t == 0) {
    float m2 = fmaxf(fmaxf(red[0], red[1]), fmaxf(red[2], red[3]));
    unsigned int b = __float_as_uint(m2);
    unsigned int u = (b & 0x80000000u) ? ~b : (b | 0x80000000u);
    atomicMax(gmax, u);
  }
}

// ---------------- ctx = kp^T @ Vg, ksum = sum_n kp (MFMA) -------------------
__global__ __launch_bounds__(256) void k_ctx(
    const u16* __restrict__ Kg, const u16* __restrict__ Vg,
    const float* __restrict__ diagK, const float* __restrict__ proj,
    const unsigned int* __restrict__ gmax,
    float* __restrict__ ctx, float* __restrict__ ksum) {
  int bh = blockIdx.x, ns = blockIdx.y, mz = blockIdx.z;
  int m0 = mz * 144;
  int nmt = mz ? 8 : 9;
  int t = threadIdx.x, lane = t & 63, w = t >> 6;
  __shared__ __align__(16) u16 prjbf[144 * 64];
  __shared__ __align__(16) u16 kpT[144 * 64];
  __shared__ __align__(16) u16 kbf[64 * 64];
  __shared__ __align__(16) u16 vbT[64 * 64];
  __shared__ float dg[64];
  __shared__ float ksl[144];
  stage_prj(proj, prjbf, t, m0, 144);
  if (t < 144) ksl[t] = 0.f;
  unsigned int u = *gmax;
  unsigned int bb = (u & 0x80000000u) ? (u & 0x7FFFFFFFu) : ~u;
  float mx = __uint_as_float(bb);
  const float dn = 0.35355339059327373f;
  const float ratio = 1.0f / sqrtf(266.0f);
  int ko = (lane >> 4) * 8;
  f32x4 acc[9];
  float ksacc[9];
#pragma unroll
  for (int i = 0; i < 9; ++i) { acc[i] = (f32x4){0.f, 0.f, 0.f, 0.f}; ksacc[i] = 0.f; }

  for (int c4 = 0; c4 < 4; ++c4) {
    int nb = ns * 256 + c4 * 64;
    for (int p = 0; p < 2; ++p) {
      int idx = t + p * 256;
      int n = idx >> 3, k0 = (idx & 7) * 8;
      uint4 src = *reinterpret_cast<const uint4*>(
          Kg + ((size_t)bh * NTOK + nb + n) * 64 + k0);
      *reinterpret_cast<uint4*>(&kbf[(n * 64 + k0) ^ ((n & 7) << 3)]) = src;
      uint4 vv = *reinterpret_cast<const uint4*>(
          Vg + ((size_t)bh * NTOK + nb + n) * 64 + k0);
      u16 pv[8];
      *reinterpret_cast<uint4*>(pv) = vv;
#pragma unroll
      for (int i = 0; i < 8; ++i) {
        int d = k0 + i;
        vbT[(d * 64 + n) ^ ((d & 7) << 3)] = pv[i];
      }
    }
    if (t < 64) dg[t] = diagK[(size_t)bh * NTOK + nb + t];
    __syncthreads();
    {
      int nl = w * 16 + (lane & 15);
      short8 a0 = *reinterpret_cast<const short8*>(&kbf[(nl * 64 + ko) ^ ((nl & 7) << 3)]);
      short8 a1 = *reinterpret_cast<const short8*>(&kbf[(nl * 64 + ko + 32) ^ ((nl & 7) << 3)]);
      float dgv[4];
#pragma unroll
      for (int r = 0; r < 4; ++r) dgv[r] = dg[w * 16 + (lane >> 4) * 4 + r];
      int n0 = w * 16 + (lane >> 4) * 4;
#pragma unroll
      for (int mt = 0; mt < 9; ++mt) {
        if (mt < nmt) {
          int lr = mt * 16 + (lane & 15);
          short8 b0 = *reinterpret_cast<const short8*>(&prjbf[(lr * 64 + ko) ^ ((lr & 7) << 3)]);
          short8 b1 = *reinterpret_cast<const short8*>(&prjbf[(lr * 64 + ko + 32) ^ ((lr & 7) << 3)]);
          f32x4 d = {0.f, 0.f, 0.f, 0.f};
          d = __builtin_amdgcn_mfma_f32_16x16x32_bf16(a0, b0, d, 0, 0, 0);
          d = __builtin_amdgcn_mfma_f32_16x16x32_bf16(a1, b1, d, 0, 0, 0);
          float kp0 = ratio * (expf(dn * d[0] - dgv[0] - mx) + 1e-4f);
          float kp1 = ratio * (expf(dn * d[1] - dgv[1] - mx) + 1e-4f);
          float kp2 = ratio * (expf(dn * d[2] - dgv[2] - mx) + 1e-4f);
          float kp3 = ratio * (expf(dn * d[3] - dgv[3] - mx) + 1e-4f);
          ushort4 pkk;
          pkk.x = f2bf(kp0); pkk.y = f2bf(kp1); pkk.z = f2bf(kp2); pkk.w = f2bf(kp3);
          *reinterpret_cast<ushort4*>(&kpT[(lr * 64 + n0) ^ ((lr & 7) << 3)]) = pkk;
          float ksp = kp0 + kp1 + kp2 + kp3;
          ksp += __shfl_xor(ksp, 16);
          ksp += __shfl_xor(ksp, 32);
          ksacc[mt] += ksp;
        }
      }
    }
    __syncthreads();
    {
      int dcol = w * 16 + (lane & 15);
      short8 vb0 = *reinterpret_cast<const short8*>(&vbT[(dcol * 64 + ko) ^ ((dcol & 7) << 3)]);
      short8 vb1 = *reinterpret_cast<const short8*>(&vbT[(dcol * 64 + ko + 32) ^ ((dcol & 7) << 3)]);
#pragma unroll
      for (int mt = 0; mt < 9; ++mt) {
        if (mt < nmt) {
          int lr = mt * 16 + (lane & 15);
          short8 a0 = *reinterpret_cast<const short8*>(&kpT[(lr * 64 + ko) ^ ((lr & 7) << 3)]);
          short8 a1 = *reinterpret_cast<const short8*>(&kpT[(lr * 64 + ko + 32) ^ ((lr & 7) << 3)]);
          acc[mt] = __builtin_amdgcn_mfma_f32_16x16x32_bf16(a0, vb0, acc[mt], 0, 0, 0);
          acc[mt] = __builtin_amdgcn_mfma_f32_16x16x32_bf16(a1, vb1, acc[mt], 0, 0, 0);
        }
      }
    }
    __syncthreads();
  }
  int dcol = w * 16 + (lane & 15);
#pragma unroll
  for (int mt = 0; mt < 9; ++mt) {
    if (mt < nmt) {
#pragma unroll
      for (int r = 0; r < 4; ++r) {
        int m = m0 + mt * 16 + (lane >> 4) * 4 + r;
        if (m < NBF)
          atomicAdd(&ctx[((size_t)bh * NBF + m) * 64 + dcol], acc[mt][r]);
      }
      if (lane < 16) atomicAdd(&ksl[mt * 16 + lane], ksacc[mt]);
    }
  }
  __syncthreads();
  if (t < 144 && m0 + t < NBF)
    atomicAdd(&ksum[(size_t)bh * NBF + m0 + t], ksl[t]);
}

// ---------------- attention row 0, one block per (b, head) ------------------
__global__ __launch_bounds__(256) void k_att(
    const int* __restrict__ ids,
    const float* __restrict__ ln1g, const float* __restrict__ ln1b,
    const float* __restrict__ Wq, const float* __restrict__ Wk,
    const float* __restrict__ Wv, const float* __restrict__ proj,
    const u16* __restrict__ hng,
    const float* __restrict__ ctx, const float* __restrict__ ksum,
    const float* __restrict__ x0, float* __restrict__ att) {
  int b = blockIdx.x, h = blockIdx.y;
  int t = threadIdx.x;
  int lane = t & 63, wg = t >> 6;
  __shared__ float hn1[64], qh[64], qpart[4][64], red[4], pol[4][64];
  __shared__ float buf[272];
  __shared__ float dots[2048];
  __shared__ float wkq[64], svec[64];
  __shared__ u16 vst[512 * 64];
  const float dn = 0.35355339059327373f;
  const float ratio = 1.0f / sqrtf(266.0f);

  if (t < 64) {
    float xv = x0[b * 64 + t];
    float mu = wredsum64(xv) * 0.015625f;
    float dv = xv - mu;
    float var = wredsum64(dv * dv) * 0.015625f;
    hn1[t] = dv * rsqrtf(var + 1e-5f) * ln1g[t] + ln1b[t];
  }
  __syncthreads();
  {
    float p = 0;
#pragma unroll
    for (int dd = 0; dd < 16; ++dd)
      p += hn1[wg * 16 + dd] * Wq[(wg * 16 + dd) * 512 + h * 64 + lane];
    qpart[wg][lane] = p;
  }
  __syncthreads();
  if (t < 64) qh[t] = qpart[0][t] + qpart[1][t] + qpart[2][t] + qpart[3][t];
  __syncthreads();

  if (h < 4) {
    int bh = b * 4 + h;
    float dq = 0;
#pragma unroll
    for (int d = 0; d < 64; ++d) dq += qh[d] * qh[d];
    dq *= 0.0625f;
    float lmax = -3e38f;
#pragma unroll
    for (int pass = 0; pass < 2; ++pass) {
      int m = t + pass * 256;
      if (m < NBF) {
        const float4* pp = reinterpret_cast<const float4*>(proj + m * 64);
        float s = 0;
#pragma unroll
        for (int q4 = 0; q4 < 16; ++q4) {
          float4 uu = pp[q4];
          s += qh[q4 * 4] * uu.x + qh[q4 * 4 + 1] * uu.y +
               qh[q4 * 4 + 2] * uu.z + qh[q4 * 4 + 3] * uu.w;
        }
        float dash = dn * s;
        buf[m] = dash;
        lmax = fmaxf(lmax, dash);
      }
    }
    float mxq = bmax256(lmax, red);
    float part = 0;
#pragma unroll
    for (int pass = 0; pass < 2; ++pass) {
      int m = t + pass * 256;
      if (m < NBF) {
        float qp = ratio * (expf(buf[m] - dq - mxq) + 1e-4f);
        buf[m] = qp;
        part += qp * ksum[(size_t)bh * NBF + m];
      }
    }
    float den = bsum256(part, red);
    __syncthreads();
    {
      float s = 0;
      for (int m = wg; m < NBF; m += 4)
        s += buf[m] * ctx[((size_t)bh * NBF + m) * 64 + lane];
      pol[wg][lane] = s;
    }
    __syncthreads();
    if (t < 64)
      att[b * 512 + h * 64 + t] =
          (pol[0][t] + pol[1][t] + pol[2][t] + pol[3][t]) / den;
  } else {
    int ch = h * 64;
    if (t < 64) {
      float s = 0;
#pragma unroll 8
      for (int j = 0; j < 64; ++j) s += Wk[t * 512 + ch + j] * qh[j];
      wkq[t] = s;
    }
    __syncthreads();
    const u16* hnb = hng + (size_t)b * NTOK * 64;
    float lmax = -3e38f;
#pragma unroll
    for (int i = 0; i < 8; ++i) {
      int n1 = t + i * 256;
      const ushort4* hr = reinterpret_cast<const ushort4*>(hnb + (size_t)n1 * 64);
      float s = 0;
#pragma unroll
      for (int d4 = 0; d4 < 16; ++d4) {
        ushort4 uu = hr[d4];
        s += wkq[d4 * 4] * bf2f(uu.x) + wkq[d4 * 4 + 1] * bf2f(uu.y) +
             wkq[d4 * 4 + 2] * bf2f(uu.z) + wkq[d4 * 4 + 3] * bf2f(uu.w);
      }
      float dv = s * 0.125f;
      if (ids[b * NTOK + n1] == 0) dv = -1e9f;
      dots[n1] = dv;
      lmax = fmaxf(lmax, dv);
    }
    float mxl = bmax256(lmax, red);
    float ps = 0;
#pragma unroll
    for (int i = 0; i < 8; ++i) {
      int n1 = t + i * 256;
      float p = expf(dots[n1] - mxl);
      dots[n1] = p;
      ps += p;
    }
    float sden = bsum256(ps, red);
    float acc = 0;
    for (int c = 0; c < 4; ++c) {
      __syncthreads();
      const ushort4* src = reinterpret_cast<const ushort4*>(hnb + (size_t)(c * 512) * 64);
      ushort4* dst = reinterpret_cast<ushort4*>(vst);
#pragma unroll
      for (int i = 0; i < 32; ++i) dst[t + i * 256] = src[t + i * 256];
      __syncthreads();
      int r0 = wg * 128;
#pragma unroll 8
      for (int r = 0; r < 128; ++r)
        acc += dots[c * 512 + r0 + r] * bf2f(vst[(r0 + r) * 64 + lane]);
    }
    __syncthreads();
    pol[wg][lane] = acc;
    __syncthreads();
    if (t < 64) svec[t] = pol[0][t] + pol[1][t] + pol[2][t] + pol[3][t];
    __syncthreads();
    {
      float p2 = 0;
#pragma unroll
      for (int dd = 0; dd < 16; ++dd)
        p2 += svec[wg * 16 + dd] * Wv[(wg * 16 + dd) * 512 + ch + lane];
      pol[wg][lane] = p2;
    }
    __syncthreads();
    if (t < 64)
      att[b * 512 + h * 64 + t] =
          (pol[0][t] + pol[1][t] + pol[2][t] + pol[3][t]) / sden;
  }
}

// ---------------- tail at position 0: Wo, FF, final LN, heads ----------------
__global__ __launch_bounds__(256) void k_fin2(
    const float* __restrict__ ln2g, const float* __restrict__ ln2b,
    const float* __restrict__ Wo,
    const float* __restrict__ W1, const float* __restrict__ b1,
    const float* __restrict__ W2, const float* __restrict__ b2,
    const float* __restrict__ lnfg, const float* __restrict__ lnfb,
    const float* __restrict__ Wout, const float* __restrict__ bout,
    const float* __restrict__ Wc1, const float* __restrict__ bc1,
    const float* __restrict__ Wc2, const float* __restrict__ bc2,
    const float* __restrict__ x0, const float* __restrict__ att,
    float* __restrict__ out) {
  int b = blockIdx.x;
  int t = threadIdx.x;
  int lane = t & 63, wg = t >> 6;
  __shared__ float o512s[512], x0s[64], part[4][64];
  __shared__ float y1[64], hn2[64], gact[256], hfin[64], repS[64], c1s[32];
  o512s[t] = att[b * 512 + t];
  o512s[t + 256] = att[b * 512 + t + 256];
  if (t < 64) x0s[t] = x0[b * 64 + t];
  __syncthreads();
  {
    float s = 0;
#pragma unroll 4
    for (int c = wg * 128; c < wg * 128 + 128; ++c) s += o512s[c] * Wo[c * 64 + lane];
    part[wg][lane] = s;
  }
  __syncthreads();
  if (t < 64) {
    float yv = x0s[t] + part[0][t] + part[1][t] + part[2][t] + part[3][t];
    y1[t] = yv;
    float mu = wredsum64(yv) * 0.015625f;
    float dv = yv - mu;
    float var = wredsum64(dv * dv) * 0.015625f;
    hn2[t] = dv * rsqrtf(var + 1e-5f) * ln2g[t] + ln2b[t];
  }
  __syncthreads();
  {
    float s = b1[t];
#pragma unroll 4
    for (int d = 0; d < 64; ++d) s += hn2[d] * W1[d * 256 + t];
    gact[t] = 0.5f * s * (1.f + erff(s * 0.7071067811865475f));
  }
  __syncthreads();
  {
    float s = 0;
#pragma unroll 4
    for (int j = wg * 64; j < wg * 64 + 64; ++j) s += gact[j] * W2[j * 64 + lane];
    part[wg][lane] = s;
  }
  __syncthreads();
  if (t < 64) {
    float y2 = x0s[t] + b2[t] + part[0][t] + part[1][t] + part[2][t] + part[3][t];
    float hm = 0.5f * (y1[t] + y2);
    float mu = wredsum64(hm) * 0.015625f;
    float dv = hm - mu;
    float var = wredsum64(dv * dv) * 0.015625f;
    hfin[t] = dv * rsqrtf(var + 1e-5f) * lnfg[t] + lnfb[t];
  }
  __syncthreads();
  {
    float s = 0;
#pragma unroll
    for (int dd = 0; dd < 16; ++dd)
      s += hfin[wg * 16 + dd] * Wout[(wg * 16 + dd) * 64 + lane];
    part[wg][lane] = s;
  }
  __syncthreads();
  if (t < 64) {
    float s = bout[t] + part[0][t] + part[1][t] + part[2][t] + part[3][t];
    repS[t] = s;
    out[16 + b * 64 + t] = s;
  }
  __syncthreads();
  if (t < 32) {
    float s = bc1[t];
#pragma unroll 4
    for (int d = 0; d < 64; ++d) s += repS[d] * Wc1[d * 32 + t];
    c1s[t] = fmaxf(s, 0.f);
  }
  __syncthreads();
  if (t < 2) {
    float s = bc2[t];
#pragma unroll
    for (int jj = 0; jj < 32; ++jj) s += c1s[jj] * Wc2[jj * 2 + t];
    out[b * 2 + t] = s;
  }
}

extern "C" void kernel_launch(void* const* d_in, const int* in_sizes, int n_in,
                              void* d_out, int out_size, void* d_ws, size_t ws_size,
                              hipStream_t stream) {
  (void)in_sizes; (void)n_in; (void)out_size; (void)ws_size;
  const int* ids = (const int*)d_in[0];
  const float* tok = (const float*)d_in[1];
  const float* ln1g = (const float*)d_in[2];
  const float* ln1b = (const float*)d_in[3];
  const float* Wq = (const float*)d_in[4];
  const float* Wk = (const float*)d_in[5];
  const float* Wv = (const float*)d_in[6];
  const float* Wo = (const float*)d_in[7];
  const float* ln2g = (const float*)d_in[8];
  const float* ln2b = (const float*)d_in[9];
  const float* W1 = (const float*)d_in[10];
  const float* b1 = (const float*)d_in[11];
  const float* W2 = (const float*)d_in[12];
  const float* b2 = (const float*)d_in[13];
  const float* lnfg = (const float*)d_in[14];
  const float* lnfb = (const float*)d_in[15];
  const float* Wout = (const float*)d_in[16];
  const float* bout = (const float*)d_in[17];
  const float* Wc1 = (const float*)d_in[18];
  const float* bc1 = (const float*)d_in[19];
  const float* Wc2 = (const float*)d_in[20];
  const float* bc2 = (const float*)d_in[21];
  const float* proj = (const float*)d_in[22];

  uint8_t* w = (uint8_t*)d_ws;
  size_t off = 0;
  const size_t big = (size_t)8 * 4 * NTOK * 64 * 2;  // 4.19 MB each
  u16* Kg = (u16*)(w + off); off += big;
  u16* Vg = (u16*)(w + off); off += big;
  u16* hng = (u16*)(w + off); off += (size_t)8 * NTOK * 64 * 2;  // 2 MB
  float* diagK = (float*)(w + off); off += (size_t)8 * 4 * NTOK * 4;
  float* ctx = (float*)(w + off); off += (size_t)8 * 4 * NBF * 64 * 4;
  float* ksum = (float*)(w + off); off += (size_t)8 * 4 * NBF * 4;
  unsigned int* gmax = (unsigned int*)(w + off); off += 4;
  off += 12;  // pad so the zero region (ctx..gmax) is a whole uint4 count
  float* x0 = (float*)(w + off); off += 64 * 8 * 4;
  float* att = (float*)(w + off); off += (size_t)8 * 512 * 4;

  k_prep<<<8 * 256, 64, 0, stream>>>(ids, tok, ln1g, ln1b, Wk, Wv, Kg, Vg, hng,
                                     diagK, x0, (uint4*)ctx);
  k_max<<<dim3(32, 16), 256, 0, stream>>>(Kg, proj, gmax);
  k_ctx<<<dim3(32, 8, 2), 256, 0, stream>>>(Kg, Vg, diagK, proj, gmax, ctx, ksum);
  k_att<<<dim3(8, 8), 256, 0, stream>>>(ids, ln1g, ln1b, Wq, Wk, Wv, proj, hng,
                                        ctx, ksum, x0, att);
  k_fin2<<<8, 256, 0, stream>>>(ln2g, ln2b, Wo, W1, b1, W2, b2, lnfg, lnfb, Wout,
                                bout, Wc1, bc1, Wc2, bc2, x0, att, (float*)d_out);
}

// Round 11
// 134.705 us; speedup vs baseline: 1.0963x; 1.0441x over previous
//
#include <hip/hip_runtime.h>
#include <math.h>

#define NTOK 2048
#define NBF 266
#define MPAD 272
// zero region: ctx (8*4*266*64 f32) + ksum (8*4*266 f32) + gmax + 12B pad
#define ZWORDS4 138321u   // uint4 count: (2179072 + 34048 + 16) / 16

typedef unsigned short u16;
typedef __attribute__((ext_vector_type(8))) short short8;
typedef __attribute__((ext_vector_type(4))) float f32x4;

__device__ __forceinline__ float bf2f(u16 u) {
  unsigned int x = ((unsigned int)u) << 16;
  return __uint_as_float(x);
}
__device__ __forceinline__ u16 f2bf(float f) {
  unsigned int x = __float_as_uint(f);
  unsigned int r = x + 0x7FFFu + ((x >> 16) & 1u);
  return (u16)(r >> 16);
}
__device__ __forceinline__ float wredsum64(float v) {
  for (int o = 32; o > 0; o >>= 1) v += __shfl_xor(v, o);
  return v;
}
__device__ __forceinline__ float bsum256(float v, float* red) {
  for (int o = 32; o > 0; o >>= 1) v += __shfl_xor(v, o);
  __syncthreads();
  if ((threadIdx.x & 63) == 0) red[threadIdx.x >> 6] = v;
  __syncthreads();
  return red[0] + red[1] + red[2] + red[3];
}
__device__ __forceinline__ float bmax256(float v, float* red) {
  for (int o = 32; o > 0; o >>= 1) v = fmaxf(v, __shfl_xor(v, o));
  __syncthreads();
  if ((threadIdx.x & 63) == 0) red[threadIdx.x >> 6] = v;
  __syncthreads();
  return fmaxf(fmaxf(red[0], red[1]), fmaxf(red[2], red[3]));
}
#define INVF_C 0.4152410118609190f

// ---- prep v4: 128 thr / 8 tokens / 4 cols per thread -> acc[8][4]=32 VGPR,
// spill impossible; wave0 = K-global cols, wave1 = V-global cols.
__global__ __launch_bounds__(128) void k_prep(
    const int* __restrict__ ids, const float* __restrict__ tok_emb,
    const float* __restrict__ ln1g, const float* __restrict__ ln1b,
    const float* __restrict__ Wk, const float* __restrict__ Wv,
    u16* __restrict__ Kg, u16* __restrict__ Vg, u16* __restrict__ hng,
    float* __restrict__ diagK, float* __restrict__ x0,
    uint4* __restrict__ zbase) {
  int blk = blockIdx.x;            // 8 * 256 blocks
  int b = blk >> 8, nt = blk & 255;
  int n0 = nt * 8;
  int t = threadIdx.x;             // 0..127
  int w = t >> 6, lane = t & 63;
  __shared__ float hn[8][64];
  __shared__ float idm[8];

  // fused zeroing of ctx/ksum/gmax (must re-zero every call): 1 word/thread
  {
    unsigned int zi = (unsigned int)blk * 128u + (unsigned int)t;
    if (zi < ZWORDS4) zbase[zi] = make_uint4(0u, 0u, 0u, 0u);
  }

  // LN: wave w handles tokens w*4 .. w*4+3
  float g = ln1g[lane], bb = ln1b[lane];
  float invp = exp2f(-INVF_C * (float)(lane & 31));
#pragma unroll
  for (int j2 = 0; j2 < 4; ++j2) {
    int j = w * 4 + j2;
    int n = n0 + j;
    int id = ids[b * NTOK + n];
    float ang = (float)n * invp;
    float pv = (lane < 32) ? sinf(ang) : cosf(ang);
    float xv = tok_emb[id * 64 + lane] + pv;
    float mu = wredsum64(xv) * 0.015625f;
    float dv = xv - mu;
    float var = wredsum64(dv * dv) * 0.015625f;
    float hv = dv * rsqrtf(var + 1e-5f) * g + bb;
    hn[j][lane] = hv;
    hng[((size_t)b * NTOK + n) * 64 + lane] = f2bf(hv);
    if (lane == 0) idm[j] = (id != 0) ? 1.f : 0.f;
    if (n == 0) x0[b * 64 + lane] = xv;
  }
  __syncthreads();

  // GEMM: thread t covers 4 global-head output cols:
  //   t < 64 : Wk cols t*4..t*4+3 ; t >= 64 : Wv cols (t-64)*4..
  float acc[8][4];
#pragma unroll
  for (int j = 0; j < 8; ++j)
#pragma unroll
    for (int i = 0; i < 4; ++i) acc[j][i] = 0.f;
  const float* wsrc = (t < 64) ? (Wk + t * 4) : (Wv + (t - 64) * 4);
  for (int d2 = 0; d2 < 64; ++d2) {
    float4 w0 = *reinterpret_cast<const float4*>(wsrc + d2 * 512);
#pragma unroll
    for (int j = 0; j < 8; ++j) {
      float hv = hn[j][d2];
      acc[j][0] += hv * w0.x; acc[j][1] += hv * w0.y;
      acc[j][2] += hv * w0.z; acc[j][3] += hv * w0.w;
    }
  }

  if (t < 64) {   // K-global: head hh = t>>4, channel offset db = (t&15)*4
    int hh = t >> 4, db = (t & 15) * 4;
    float invf0 = exp2f(-INVF_C * (float)(db >> 1));
    float invf1 = exp2f(-INVF_C * (float)((db >> 1) + 1));
#pragma unroll
    for (int j = 0; j < 8; ++j) {
      int n = n0 + j;
      float a0 = (float)n * invf0, a1 = (float)n * invf1;
      float s0 = sinf(a0), c0 = cosf(a0);
      float s1 = sinf(a1), c1 = cosf(a1);
      float kr0 = acc[j][0] * c0 - acc[j][1] * s0;
      float kr1 = acc[j][1] * c0 + acc[j][0] * s0;
      float kr2 = acc[j][2] * c1 - acc[j][3] * s1;
      float kr3 = acc[j][3] * c1 + acc[j][2] * s1;
      float dq = kr0 * kr0 + kr1 * kr1 + kr2 * kr2 + kr3 * kr3;
      dq += __shfl_xor(dq, 1);
      dq += __shfl_xor(dq, 2);
      dq += __shfl_xor(dq, 4);
      dq += __shfl_xor(dq, 8);   // 16-thread head group
      size_t hb = (size_t)(b * 4 + hh) * NTOK + n;
      if ((t & 15) == 0) diagK[hb] = dq * 0.0625f;  // 0.5*dn*dn = 1/16
      ushort4 s;
      s.x = f2bf(kr0); s.y = f2bf(kr1); s.z = f2bf(kr2); s.w = f2bf(kr3);
      *reinterpret_cast<ushort4*>(Kg + hb * 64 + db) = s;
    }
  } else {        // V-global: mask, write Vg
    int tv = t - 64;
    int hh = tv >> 4, db = (tv & 15) * 4;
#pragma unroll
    for (int j = 0; j < 8; ++j) {
      int n = n0 + j;
      float m = idm[j];
      ushort4 vv;
      vv.x = f2bf(acc[j][0] * m); vv.y = f2bf(acc[j][1] * m);
      vv.z = f2bf(acc[j][2] * m); vv.w = f2bf(acc[j][3] * m);
      *reinterpret_cast<ushort4*>(
          Vg + ((size_t)(b * 4 + hh) * NTOK + n) * 64 + db) = vv;
    }
  }
}

// ---- stage proj rows [m0, m0+rows) into swizzled bf16 LDS [rows][64] -------
__device__ __forceinline__ void stage_prj(const float* __restrict__ proj,
                                          u16* prjbf, int t, int m0, int rows) {
  for (int c = t; c < rows * 8; c += 256) {
    int r = c >> 3, k0 = (c & 7) * 8;
    int m = m0 + r;
    int e = (r * 64 + k0) ^ ((r & 7) << 3);
    uint4 pk;
    if (m < NBF) {
      const float4* ps = reinterpret_cast<const float4*>(proj + m * 64 + k0);
      float4 p0 = ps[0], p1 = ps[1];
      pk.x = (unsigned)f2bf(p0.x) | ((unsigned)f2bf(p0.y) << 16);
      pk.y = (unsigned)f2bf(p0.z) | ((unsigned)f2bf(p0.w) << 16);
      pk.z = (unsigned)f2bf(p1.x) | ((unsigned)f2bf(p1.y) << 16);
      pk.w = (unsigned)f2bf(p1.z) | ((unsigned)f2bf(p1.w) << 16);
    } else {
      pk.x = pk.y = pk.z = pk.w = 0u;
    }
    *reinterpret_cast<uint4*>(&prjbf[e]) = pk;
  }
}

// ---------------- global max over dash = dn * Kg @ proj^T (MFMA) ------------
__global__ __launch_bounds__(256) void k_max(
    const u16* __restrict__ Kg, const float* __restrict__ proj,
    unsigned int* __restrict__ gmax) {
  int bh = blockIdx.x, ns = blockIdx.y;
  int t = threadIdx.x, lane = t & 63, w = t >> 6;
  __shared__ __align__(16) u16 prjbf[MPAD * 64];
  __shared__ __align__(16) u16 kbf[64 * 64];
  __shared__ float red[4];
  stage_prj(proj, prjbf, t, 0, MPAD);
  float mv = -3e38f;
  int ko = (lane >> 4) * 8;
  for (int c4 = 0; c4 < 2; ++c4) {
    int nb = ns * 128 + c4 * 64;
    __syncthreads();
    for (int p = 0; p < 2; ++p) {
      int idx = t + p * 256;
      int n = idx >> 3, k0 = (idx & 7) * 8;
      uint4 src = *reinterpret_cast<const uint4*>(
          Kg + ((size_t)bh * NTOK + nb + n) * 64 + k0);
      *reinterpret_cast<uint4*>(&kbf[(n * 64 + k0) ^ ((n & 7) << 3)]) = src;
    }
    __syncthreads();
    int nl = w * 16 + (lane & 15);
    short8 a0 = *reinterpret_cast<const short8*>(&kbf[(nl * 64 + ko) ^ ((nl & 7) << 3)]);
    short8 a1 = *reinterpret_cast<const short8*>(&kbf[(nl * 64 + ko + 32) ^ ((nl & 7) << 3)]);
#pragma unroll
    for (int mt = 0; mt < 17; ++mt) {
      int m = mt * 16 + (lane & 15);
      short8 b0 = *reinterpret_cast<const short8*>(&prjbf[(m * 64 + ko) ^ ((m & 7) << 3)]);
      short8 b1 = *reinterpret_cast<const short8*>(&prjbf[(m * 64 + ko + 32) ^ ((m & 7) << 3)]);
      f32x4 d = {0.f, 0.f, 0.f, 0.f};
      d = __builtin_amdgcn_mfma_f32_16x16x32_bf16(a0, b0, d, 0, 0, 0);
      d = __builtin_amdgcn_mfma_f32_16x16x32_bf16(a1, b1, d, 0, 0, 0);
      if (m < NBF) {
        mv = fmaxf(mv, fmaxf(fmaxf(d[0], d[1]), fmaxf(d[2], d[3])));
      }
    }
  }
  mv *= 0.35355339059327373f;
  for (int o = 32; o > 0; o >>= 1) mv = fmaxf(mv, __shfl_xor(mv, o));
  __syncthreads();
  if (lane == 0) red[w] = mv;
  __syncthreads();
  if (t == 0) {
    float m2 = fmaxf(fmaxf(red[0], red[1]), fmaxf(red[2], red[3]));
    unsigned int b = __float_as_uint(m2);
    unsigned int u = (b & 0x80000000u) ? ~b : (b | 0x80000000u);
    atomicMax(gmax, u);
  }
}

// ---------------- ctx = kp^T @ Vg, ksum = sum_n kp (MFMA) -------------------
__global__ __launch_bounds__(256) void k_ctx(
    const u16* __restrict__ Kg, const u16* __restrict__ Vg,
    const float* __restrict__ diagK, const float* __restrict__ proj,
    const unsigned int* __restrict__ gmax,
    float* __restrict__ ctx, float* __restrict__ ksum) {
  int bh = blockIdx.x, ns = blockIdx.y, mz = blockIdx.z;
  int m0 = mz * 144;
  int nmt = mz ? 8 : 9;
  int t = threadIdx.x, lane = t & 63, w = t >> 6;
  __shared__ __align__(16) u16 prjbf[144 * 64];
  __shared__ __align__(16) u16 kpT[144 * 64];
  __shared__ __align__(16) u16 kbf[64 * 64];
  __shared__ __align__(16) u16 vbT[64 * 64];
  __shared__ float dg[64];
  __shared__ float ksl[144];
  stage_prj(proj, prjbf, t, m0, 144);
  if (t < 144) ksl[t] = 0.f;
  unsigned int u = *gmax;
  unsigned int bb = (u & 0x80000000u) ? (u & 0x7FFFFFFFu) : ~u;
  float mx = __uint_as_float(bb);
  const float dn = 0.35355339059327373f;
  const float ratio = 1.0f / sqrtf(266.0f);
  int ko = (lane >> 4) * 8;
  f32x4 acc[9];
  float ksacc[9];
#pragma unroll
  for (int i = 0; i < 9; ++i) { acc[i] = (f32x4){0.f, 0.f, 0.f, 0.f}; ksacc[i] = 0.f; }

  for (int c4 = 0; c4 < 4; ++c4) {
    int nb = ns * 256 + c4 * 64;
    for (int p = 0; p < 2; ++p) {
      int idx = t + p * 256;
      int n = idx >> 3, k0 = (idx & 7) * 8;
      uint4 src = *reinterpret_cast<const uint4*>(
          Kg + ((size_t)bh * NTOK + nb + n) * 64 + k0);
      *reinterpret_cast<uint4*>(&kbf[(n * 64 + k0) ^ ((n & 7) << 3)]) = src;
      uint4 vv = *reinterpret_cast<const uint4*>(
          Vg + ((size_t)bh * NTOK + nb + n) * 64 + k0);
      u16 pv[8];
      *reinterpret_cast<uint4*>(pv) = vv;
#pragma unroll
      for (int i = 0; i < 8; ++i) {
        int d = k0 + i;
        vbT[(d * 64 + n) ^ ((d & 7) << 3)] = pv[i];
      }
    }
    if (t < 64) dg[t] = diagK[(size_t)bh * NTOK + nb + t];
    __syncthreads();
    {
      int nl = w * 16 + (lane & 15);
      short8 a0 = *reinterpret_cast<const short8*>(&kbf[(nl * 64 + ko) ^ ((nl & 7) << 3)]);
      short8 a1 = *reinterpret_cast<const short8*>(&kbf[(nl * 64 + ko + 32) ^ ((nl & 7) << 3)]);
      float dgv[4];
#pragma unroll
      for (int r = 0; r < 4; ++r) dgv[r] = dg[w * 16 + (lane >> 4) * 4 + r];
      int n0 = w * 16 + (lane >> 4) * 4;
#pragma unroll
      for (int mt = 0; mt < 9; ++mt) {
        if (mt < nmt) {
          int lr = mt * 16 + (lane & 15);
          short8 b0 = *reinterpret_cast<const short8*>(&prjbf[(lr * 64 + ko) ^ ((lr & 7) << 3)]);
          short8 b1 = *reinterpret_cast<const short8*>(&prjbf[(lr * 64 + ko + 32) ^ ((lr & 7) << 3)]);
          f32x4 d = {0.f, 0.f, 0.f, 0.f};
          d = __builtin_amdgcn_mfma_f32_16x16x32_bf16(a0, b0, d, 0, 0, 0);
          d = __builtin_amdgcn_mfma_f32_16x16x32_bf16(a1, b1, d, 0, 0, 0);
          float kp0 = ratio * (expf(dn * d[0] - dgv[0] - mx) + 1e-4f);
          float kp1 = ratio * (expf(dn * d[1] - dgv[1] - mx) + 1e-4f);
          float kp2 = ratio * (expf(dn * d[2] - dgv[2] - mx) + 1e-4f);
          float kp3 = ratio * (expf(dn * d[3] - dgv[3] - mx) + 1e-4f);
          ushort4 pkk;
          pkk.x = f2bf(kp0); pkk.y = f2bf(kp1); pkk.z = f2bf(kp2); pkk.w = f2bf(kp3);
          *reinterpret_cast<ushort4*>(&kpT[(lr * 64 + n0) ^ ((lr & 7) << 3)]) = pkk;
          float ksp = kp0 + kp1 + kp2 + kp3;
          ksp += __shfl_xor(ksp, 16);
          ksp += __shfl_xor(ksp, 32);
          ksacc[mt] += ksp;
        }
      }
    }
    __syncthreads();
    {
      int dcol = w * 16 + (lane & 15);
      short8 vb0 = *reinterpret_cast<const short8*>(&vbT[(dcol * 64 + ko) ^ ((dcol & 7) << 3)]);
      short8 vb1 = *reinterpret_cast<const short8*>(&vbT[(dcol * 64 + ko + 32) ^ ((dcol & 7) << 3)]);
#pragma unroll
      for (int mt = 0; mt < 9; ++mt) {
        if (mt < nmt) {
          int lr = mt * 16 + (lane & 15);
          short8 a0 = *reinterpret_cast<const short8*>(&kpT[(lr * 64 + ko) ^ ((lr & 7) << 3)]);
          short8 a1 = *reinterpret_cast<const short8*>(&kpT[(lr * 64 + ko + 32) ^ ((lr & 7) << 3)]);
          acc[mt] = __builtin_amdgcn_mfma_f32_16x16x32_bf16(a0, vb0, acc[mt], 0, 0, 0);
          acc[mt] = __builtin_amdgcn_mfma_f32_16x16x32_bf16(a1, vb1, acc[mt], 0, 0, 0);
        }
      }
    }
    __syncthreads();
  }
  int dcol = w * 16 + (lane & 15);
#pragma unroll
  for (int mt = 0; mt < 9; ++mt) {
    if (mt < nmt) {
#pragma unroll
      for (int r = 0; r < 4; ++r) {
        int m = m0 + mt * 16 + (lane >> 4) * 4 + r;
        if (m < NBF)
          atomicAdd(&ctx[((size_t)bh * NBF + m) * 64 + dcol], acc[mt][r]);
      }
      if (lane < 16) atomicAdd(&ksl[mt * 16 + lane], ksacc[mt]);
    }
  }
  __syncthreads();
  if (t < 144 && m0 + t < NBF)
    atomicAdd(&ksum[(size_t)bh * NBF + m0 + t], ksl[t]);
}

// ---------------- attention row 0, one block per (b, head) ------------------
__global__ __launch_bounds__(256) void k_att(
    const int* __restrict__ ids,
    const float* __restrict__ ln1g, const float* __restrict__ ln1b,
    const float* __restrict__ Wq, const float* __restrict__ Wk,
    const float* __restrict__ Wv, const float* __restrict__ proj,
    const u16* __restrict__ hng,
    const float* __restrict__ ctx, const float* __restrict__ ksum,
    const float* __restrict__ x0, float* __restrict__ att) {
  int b = blockIdx.x, h = blockIdx.y;
  int t = threadIdx.x;
  int lane = t & 63, wg = t >> 6;
  __shared__ float hn1[64], qh[64], qpart[4][64], red[4], pol[4][64];
  __shared__ float buf[272];
  __shared__ float dots[2048];
  __shared__ float wkq[64], svec[64];
  __shared__ u16 vst[512 * 64];
  const float dn = 0.35355339059327373f;
  const float ratio = 1.0f / sqrtf(266.0f);

  if (t < 64) {
    float xv = x0[b * 64 + t];
    float mu = wredsum64(xv) * 0.015625f;
    float dv = xv - mu;
    float var = wredsum64(dv * dv) * 0.015625f;
    hn1[t] = dv * rsqrtf(var + 1e-5f) * ln1g[t] + ln1b[t];
  }
  __syncthreads();
  {
    float p = 0;
#pragma unroll
    for (int dd = 0; dd < 16; ++dd)
      p += hn1[wg * 16 + dd] * Wq[(wg * 16 + dd) * 512 + h * 64 + lane];
    qpart[wg][lane] = p;
  }
  __syncthreads();
  if (t < 64) qh[t] = qpart[0][t] + qpart[1][t] + qpart[2][t] + qpart[3][t];
  __syncthreads();

  if (h < 4) {
    int bh = b * 4 + h;
    float dq = 0;
#pragma unroll
    for (int d = 0; d < 64; ++d) dq += qh[d] * qh[d];
    dq *= 0.0625f;
    float lmax = -3e38f;
#pragma unroll
    for (int pass = 0; pass < 2; ++pass) {
      int m = t + pass * 256;
      if (m < NBF) {
        const float4* pp = reinterpret_cast<const float4*>(proj + m * 64);
        float s = 0;
#pragma unroll
        for (int q4 = 0; q4 < 16; ++q4) {
          float4 uu = pp[q4];
          s += qh[q4 * 4] * uu.x + qh[q4 * 4 + 1] * uu.y +
               qh[q4 * 4 + 2] * uu.z + qh[q4 * 4 + 3] * uu.w;
        }
        float dash = dn * s;
        buf[m] = dash;
        lmax = fmaxf(lmax, dash);
      }
    }
    float mxq = bmax256(lmax, red);
    float part = 0;
#pragma unroll
    for (int pass = 0; pass < 2; ++pass) {
      int m = t + pass * 256;
      if (m < NBF) {
        float qp = ratio * (expf(buf[m] - dq - mxq) + 1e-4f);
        buf[m] = qp;
        part += qp * ksum[(size_t)bh * NBF + m];
      }
    }
    float den = bsum256(part, red);
    __syncthreads();
    {
      float s = 0;
      for (int m = wg; m < NBF; m += 4)
        s += buf[m] * ctx[((size_t)bh * NBF + m) * 64 + lane];
      pol[wg][lane] = s;
    }
    __syncthreads();
    if (t < 64)
      att[b * 512 + h * 64 + t] =
          (pol[0][t] + pol[1][t] + pol[2][t] + pol[3][t]) / den;
  } else {
    int ch = h * 64;
    if (t < 64) {
      float s = 0;
#pragma unroll 8
      for (int j = 0; j < 64; ++j) s += Wk[t * 512 + ch + j] * qh[j];
      wkq[t] = s;
    }
    __syncthreads();
    const u16* hnb = hng + (size_t)b * NTOK * 64;
    float lmax = -3e38f;
#pragma unroll
    for (int i = 0; i < 8; ++i) {
      int n1 = t + i * 256;
      const ushort4* hr = reinterpret_cast<const ushort4*>(hnb + (size_t)n1 * 64);
      float s = 0;
#pragma unroll
      for (int d4 = 0; d4 < 16; ++d4) {
        ushort4 uu = hr[d4];
        s += wkq[d4 * 4] * bf2f(uu.x) + wkq[d4 * 4 + 1] * bf2f(uu.y) +
             wkq[d4 * 4 + 2] * bf2f(uu.z) + wkq[d4 * 4 + 3] * bf2f(uu.w);
      }
      float dv = s * 0.125f;
      if (ids[b * NTOK + n1] == 0) dv = -1e9f;
      dots[n1] = dv;
      lmax = fmaxf(lmax, dv);
    }
    float mxl = bmax256(lmax, red);
    float ps = 0;
#pragma unroll
    for (int i = 0; i < 8; ++i) {
      int n1 = t + i * 256;
      float p = expf(dots[n1] - mxl);
      dots[n1] = p;
      ps += p;
    }
    float sden = bsum256(ps, red);
    float acc = 0;
    for (int c = 0; c < 4; ++c) {
      __syncthreads();
      const ushort4* src = reinterpret_cast<const ushort4*>(hnb + (size_t)(c * 512) * 64);
      ushort4* dst = reinterpret_cast<ushort4*>(vst);
#pragma unroll
      for (int i = 0; i < 32; ++i) dst[t + i * 256] = src[t + i * 256];
      __syncthreads();
      int r0 = wg * 128;
#pragma unroll 8
      for (int r = 0; r < 128; ++r)
        acc += dots[c * 512 + r0 + r] * bf2f(vst[(r0 + r) * 64 + lane]);
    }
    __syncthreads();
    pol[wg][lane] = acc;
    __syncthreads();
    if (t < 64) svec[t] = pol[0][t] + pol[1][t] + pol[2][t] + pol[3][t];
    __syncthreads();
    {
      float p2 = 0;
#pragma unroll
      for (int dd = 0; dd < 16; ++dd)
        p2 += svec[wg * 16 + dd] * Wv[(wg * 16 + dd) * 512 + ch + lane];
      pol[wg][lane] = p2;
    }
    __syncthreads();
    if (t < 64)
      att[b * 512 + h * 64 + t] =
          (pol[0][t] + pol[1][t] + pol[2][t] + pol[3][t]) / sden;
  }
}

// ---------------- tail at position 0: Wo, FF, final LN, heads ----------------
__global__ __launch_bounds__(256) void k_fin2(
    const float* __restrict__ ln2g, const float* __restrict__ ln2b,
    const float* __restrict__ Wo,
    const float* __restrict__ W1, const float* __restrict__ b1,
    const float* __restrict__ W2, const float* __restrict__ b2,
    const float* __restrict__ lnfg, const float* __restrict__ lnfb,
    const float* __restrict__ Wout, const float* __restrict__ bout,
    const float* __restrict__ Wc1, const float* __restrict__ bc1,
    const float* __restrict__ Wc2, const float* __restrict__ bc2,
    const float* __restrict__ x0, const float* __restrict__ att,
    float* __restrict__ out) {
  int b = blockIdx.x;
  int t = threadIdx.x;
  int lane = t & 63, wg = t >> 6;
  __shared__ float o512s[512], x0s[64], part[4][64];
  __shared__ float y1[64], hn2[64], gact[256], hfin[64], repS[64], c1s[32];
  o512s[t] = att[b * 512 + t];
  o512s[t + 256] = att[b * 512 + t + 256];
  if (t < 64) x0s[t] = x0[b * 64 + t];
  __syncthreads();
  {
    float s = 0;
#pragma unroll 4
    for (int c = wg * 128; c < wg * 128 + 128; ++c) s += o512s[c] * Wo[c * 64 + lane];
    part[wg][lane] = s;
  }
  __syncthreads();
  if (t < 64) {
    float yv = x0s[t] + part[0][t] + part[1][t] + part[2][t] + part[3][t];
    y1[t] = yv;
    float mu = wredsum64(yv) * 0.015625f;
    float dv = yv - mu;
    float var = wredsum64(dv * dv) * 0.015625f;
    hn2[t] = dv * rsqrtf(var + 1e-5f) * ln2g[t] + ln2b[t];
  }
  __syncthreads();
  {
    float s = b1[t];
#pragma unroll 4
    for (int d = 0; d < 64; ++d) s += hn2[d] * W1[d * 256 + t];
    gact[t] = 0.5f * s * (1.f + erff(s * 0.7071067811865475f));
  }
  __syncthreads();
  {
    float s = 0;
#pragma unroll 4
    for (int j = wg * 64; j < wg * 64 + 64; ++j) s += gact[j] * W2[j * 64 + lane];
    part[wg][lane] = s;
  }
  __syncthreads();
  if (t < 64) {
    float y2 = x0s[t] + b2[t] + part[0][t] + part[1][t] + part[2][t] + part[3][t];
    float hm = 0.5f * (y1[t] + y2);
    float mu = wredsum64(hm) * 0.015625f;
    float dv = hm - mu;
    float var = wredsum64(dv * dv) * 0.015625f;
    hfin[t] = dv * rsqrtf(var + 1e-5f) * lnfg[t] + lnfb[t];
  }
  __syncthreads();
  {
    float s = 0;
#pragma unroll
    for (int dd = 0; dd < 16; ++dd)
      s += hfin[wg * 16 + dd] * Wout[(wg * 16 + dd) * 64 + lane];
    part[wg][lane] = s;
  }
  __syncthreads();
  if (t < 64) {
    float s = bout[t] + part[0][t] + part[1][t] + part[2][t] + part[3][t];
    repS[t] = s;
    out[16 + b * 64 + t] = s;
  }
  __syncthreads();
  if (t < 32) {
    float s = bc1[t];
#pragma unroll 4
    for (int d = 0; d < 64; ++d) s += repS[d] * Wc1[d * 32 + t];
    c1s[t] = fmaxf(s, 0.f);
  }
  __syncthreads();
  if (t < 2) {
    float s = bc2[t];
#pragma unroll
    for (int jj = 0; jj < 32; ++jj) s += c1s[jj] * Wc2[jj * 2 + t];
    out[b * 2 + t] = s;
  }
}

extern "C" void kernel_launch(void* const* d_in, const int* in_sizes, int n_in,
                              void* d_out, int out_size, void* d_ws, size_t ws_size,
                              hipStream_t stream) {
  (void)in_sizes; (void)n_in; (void)out_size; (void)ws_size;
  const int* ids = (const int*)d_in[0];
  const float* tok = (const float*)d_in[1];
  const float* ln1g = (const float*)d_in[2];
  const float* ln1b = (const float*)d_in[3];
  const float* Wq = (const float*)d_in[4];
  const float* Wk = (const float*)d_in[5];
  const float* Wv = (const float*)d_in[6];
  const float* Wo = (const float*)d_in[7];
  const float* ln2g = (const float*)d_in[8];
  const float* ln2b = (const float*)d_in[9];
  const float* W1 = (const float*)d_in[10];
  const float* b1 = (const float*)d_in[11];
  const float* W2 = (const float*)d_in[12];
  const float* b2 = (const float*)d_in[13];
  const float* lnfg = (const float*)d_in[14];
  const float* lnfb = (const float*)d_in[15];
  const float* Wout = (const float*)d_in[16];
  const float* bout = (const float*)d_in[17];
  const float* Wc1 = (const float*)d_in[18];
  const float* bc1 = (const float*)d_in[19];
  const float* Wc2 = (const float*)d_in[20];
  const float* bc2 = (const float*)d_in[21];
  const float* proj = (const float*)d_in[22];

  uint8_t* w = (uint8_t*)d_ws;
  size_t off = 0;
  const size_t big = (size_t)8 * 4 * NTOK * 64 * 2;  // 4.19 MB each
  u16* Kg = (u16*)(w + off); off += big;
  u16* Vg = (u16*)(w + off); off += big;
  u16* hng = (u16*)(w + off); off += (size_t)8 * NTOK * 64 * 2;  // 2 MB
  float* diagK = (float*)(w + off); off += (size_t)8 * 4 * NTOK * 4;
  float* ctx = (float*)(w + off); off += (size_t)8 * 4 * NBF * 64 * 4;
  float* ksum = (float*)(w + off); off += (size_t)8 * 4 * NBF * 4;
  unsigned int* gmax = (unsigned int*)(w + off); off += 4;
  off += 12;  // pad so the zero region (ctx..gmax) is a whole uint4 count
  float* x0 = (float*)(w + off); off += 64 * 8 * 4;
  float* att = (float*)(w + off); off += (size_t)8 * 512 * 4;

  k_prep<<<8 * 256, 128, 0, stream>>>(ids, tok, ln1g, ln1b, Wk, Wv, Kg, Vg, hng,
                                      diagK, x0, (uint4*)ctx);
  k_max<<<dim3(32, 16), 256, 0, stream>>>(Kg, proj, gmax);
  k_ctx<<<dim3(32, 8, 2), 256, 0, stream>>>(Kg, Vg, diagK, proj, gmax, ctx, ksum);
  k_att<<<dim3(8, 8), 256, 0, stream>>>(ids, ln1g, ln1b, Wq, Wk, Wv, proj, hng,
                                        ctx, ksum, x0, att);
  k_fin2<<<8, 256, 0, stream>>>(ln2g, ln2b, Wo, W1, b1, W2, b2, lnfg, lnfb, Wout,
                                bout, Wc1, bc1, Wc2, bc2, x0, att, (float*)d_out);
}

// Round 12
// 119.655 us; speedup vs baseline: 1.2342x; 1.1258x over previous
//
#include <hip/hip_runtime.h>
#include <math.h>

#define NTOK 2048
#define NBF 266
#define MPAD 272
// zero region: ctx (8*4*266*64 f32) + ksum (8*4*266 f32) + gmax + 12B pad
#define ZWORDS4 138321u   // uint4 count: (2179072 + 34048 + 16) / 16

typedef unsigned short u16;
typedef __attribute__((ext_vector_type(8))) short short8;
typedef __attribute__((ext_vector_type(4))) float f32x4;

__device__ __forceinline__ float bf2f(u16 u) {
  unsigned int x = ((unsigned int)u) << 16;
  return __uint_as_float(x);
}
__device__ __forceinline__ u16 f2bf(float f) {
  unsigned int x = __float_as_uint(f);
  unsigned int r = x + 0x7FFFu + ((x >> 16) & 1u);
  return (u16)(r >> 16);
}
__device__ __forceinline__ float wredsum64(float v) {
  for (int o = 32; o > 0; o >>= 1) v += __shfl_xor(v, o);
  return v;
}
__device__ __forceinline__ float bsum256(float v, float* red) {
  for (int o = 32; o > 0; o >>= 1) v += __shfl_xor(v, o);
  __syncthreads();
  if ((threadIdx.x & 63) == 0) red[threadIdx.x >> 6] = v;
  __syncthreads();
  return red[0] + red[1] + red[2] + red[3];
}
__device__ __forceinline__ float bmax256(float v, float* red) {
  for (int o = 32; o > 0; o >>= 1) v = fmaxf(v, __shfl_xor(v, o));
  __syncthreads();
  if ((threadIdx.x & 63) == 0) red[threadIdx.x >> 6] = v;
  __syncthreads();
  return fmaxf(fmaxf(red[0], red[1]), fmaxf(red[2], red[3]));
}
#define INVF_C 0.4152410118609190f

// ---- sin/cos table: sc[n*32+i] = (sin(n*invf_i), cos(n*invf_i)) ------------
__global__ __launch_bounds__(256) void k_tab(float2* __restrict__ sc) {
  int idx = blockIdx.x * 256 + threadIdx.x;   // 65536
  int n = idx >> 5, i = idx & 31;
  float ang = (float)n * exp2f(-INVF_C * (float)i);
  sc[idx] = make_float2(sinf(ang), cosf(ang));
}

// ---- prep v5: 128 thr / 8 tokens / 4 cols per thread; trig via table -------
__global__ __launch_bounds__(128) void k_prep(
    const int* __restrict__ ids, const float* __restrict__ tok_emb,
    const float* __restrict__ ln1g, const float* __restrict__ ln1b,
    const float* __restrict__ Wk, const float* __restrict__ Wv,
    const float2* __restrict__ sc,
    u16* __restrict__ Kg, u16* __restrict__ Vg, u16* __restrict__ hng,
    float* __restrict__ diagK, float* __restrict__ x0,
    uint4* __restrict__ zbase) {
  int blk = blockIdx.x;            // 8 * 256 blocks
  int b = blk >> 8, nt = blk & 255;
  int n0 = nt * 8;
  int t = threadIdx.x;             // 0..127
  int w = t >> 6, lane = t & 63;
  __shared__ float hn[8][64];
  __shared__ float idm[8];

  // fused zeroing of ctx/ksum/gmax (must re-zero every call): 1 word/thread
  {
    unsigned int zi = (unsigned int)blk * 128u + (unsigned int)t;
    if (zi < ZWORDS4) zbase[zi] = make_uint4(0u, 0u, 0u, 0u);
  }

  // LN: wave w handles tokens w*4 .. w*4+3; posenc from table
  float g = ln1g[lane], bb = ln1b[lane];
#pragma unroll
  for (int j2 = 0; j2 < 4; ++j2) {
    int j = w * 4 + j2;
    int n = n0 + j;
    int id = ids[b * NTOK + n];
    float2 p = sc[n * 32 + (lane & 31)];
    float pv = (lane < 32) ? p.x : p.y;
    float xv = tok_emb[id * 64 + lane] + pv;
    float mu = wredsum64(xv) * 0.015625f;
    float dv = xv - mu;
    float var = wredsum64(dv * dv) * 0.015625f;
    float hv = dv * rsqrtf(var + 1e-5f) * g + bb;
    hn[j][lane] = hv;
    hng[((size_t)b * NTOK + n) * 64 + lane] = f2bf(hv);
    if (lane == 0) idm[j] = (id != 0) ? 1.f : 0.f;
    if (n == 0) x0[b * 64 + lane] = xv;
  }
  __syncthreads();

  // GEMM: thread t covers 4 global-head output cols:
  //   t < 64 : Wk cols t*4..t*4+3 ; t >= 64 : Wv cols (t-64)*4..
  float acc[8][4];
#pragma unroll
  for (int j = 0; j < 8; ++j)
#pragma unroll
    for (int i = 0; i < 4; ++i) acc[j][i] = 0.f;
  const float* wsrc = (t < 64) ? (Wk + t * 4) : (Wv + (t - 64) * 4);
  for (int d2 = 0; d2 < 64; ++d2) {
    float4 w0 = *reinterpret_cast<const float4*>(wsrc + d2 * 512);
#pragma unroll
    for (int j = 0; j < 8; ++j) {
      float hv = hn[j][d2];
      acc[j][0] += hv * w0.x; acc[j][1] += hv * w0.y;
      acc[j][2] += hv * w0.z; acc[j][3] += hv * w0.w;
    }
  }

  if (t < 64) {   // K-global: head hh = t>>4, channel offset db = (t&15)*4
    int hh = t >> 4, db = (t & 15) * 4;
    int i0 = (t & 15) * 2;
#pragma unroll
    for (int j = 0; j < 8; ++j) {
      int n = n0 + j;
      float2 t0 = sc[n * 32 + i0];
      float2 t1 = sc[n * 32 + i0 + 1];
      float s0 = t0.x, c0 = t0.y, s1 = t1.x, c1 = t1.y;
      float kr0 = acc[j][0] * c0 - acc[j][1] * s0;
      float kr1 = acc[j][1] * c0 + acc[j][0] * s0;
      float kr2 = acc[j][2] * c1 - acc[j][3] * s1;
      float kr3 = acc[j][3] * c1 + acc[j][2] * s1;
      float dq = kr0 * kr0 + kr1 * kr1 + kr2 * kr2 + kr3 * kr3;
      dq += __shfl_xor(dq, 1);
      dq += __shfl_xor(dq, 2);
      dq += __shfl_xor(dq, 4);
      dq += __shfl_xor(dq, 8);   // 16-thread head group
      size_t hb = (size_t)(b * 4 + hh) * NTOK + n;
      if ((t & 15) == 0) diagK[hb] = dq * 0.0625f;  // 0.5*dn*dn = 1/16
      ushort4 s;
      s.x = f2bf(kr0); s.y = f2bf(kr1); s.z = f2bf(kr2); s.w = f2bf(kr3);
      *reinterpret_cast<ushort4*>(Kg + hb * 64 + db) = s;
    }
  } else {        // V-global: mask, write Vg
    int tv = t - 64;
    int hh = tv >> 4, db = (tv & 15) * 4;
#pragma unroll
    for (int j = 0; j < 8; ++j) {
      int n = n0 + j;
      float m = idm[j];
      ushort4 vv;
      vv.x = f2bf(acc[j][0] * m); vv.y = f2bf(acc[j][1] * m);
      vv.z = f2bf(acc[j][2] * m); vv.w = f2bf(acc[j][3] * m);
      *reinterpret_cast<ushort4*>(
          Vg + ((size_t)(b * 4 + hh) * NTOK + n) * 64 + db) = vv;
    }
  }
}

// ---- stage proj rows [m0, m0+rows) into swizzled bf16 LDS [rows][64] -------
__device__ __forceinline__ void stage_prj(const float* __restrict__ proj,
                                          u16* prjbf, int t, int m0, int rows) {
  for (int c = t; c < rows * 8; c += 256) {
    int r = c >> 3, k0 = (c & 7) * 8;
    int m = m0 + r;
    int e = (r * 64 + k0) ^ ((r & 7) << 3);
    uint4 pk;
    if (m < NBF) {
      const float4* ps = reinterpret_cast<const float4*>(proj + m * 64 + k0);
      float4 p0 = ps[0], p1 = ps[1];
      pk.x = (unsigned)f2bf(p0.x) | ((unsigned)f2bf(p0.y) << 16);
      pk.y = (unsigned)f2bf(p0.z) | ((unsigned)f2bf(p0.w) << 16);
      pk.z = (unsigned)f2bf(p1.x) | ((unsigned)f2bf(p1.y) << 16);
      pk.w = (unsigned)f2bf(p1.z) | ((unsigned)f2bf(p1.w) << 16);
    } else {
      pk.x = pk.y = pk.z = pk.w = 0u;
    }
    *reinterpret_cast<uint4*>(&prjbf[e]) = pk;
  }
}

// ---------------- global max over dash = dn * Kg @ proj^T (MFMA) ------------
__global__ __launch_bounds__(256) void k_max(
    const u16* __restrict__ Kg, const float* __restrict__ proj,
    unsigned int* __restrict__ gmax) {
  int bh = blockIdx.x, ns = blockIdx.y;
  int t = threadIdx.x, lane = t & 63, w = t >> 6;
  __shared__ __align__(16) u16 prjbf[MPAD * 64];
  __shared__ __align__(16) u16 kbf[64 * 64];
  __shared__ float red[4];
  stage_prj(proj, prjbf, t, 0, MPAD);
  float mv = -3e38f;
  int ko = (lane >> 4) * 8;
  for (int c4 = 0; c4 < 2; ++c4) {
    int nb = ns * 128 + c4 * 64;
    __syncthreads();
    for (int p = 0; p < 2; ++p) {
      int idx = t + p * 256;
      int n = idx >> 3, k0 = (idx & 7) * 8;
      uint4 src = *reinterpret_cast<const uint4*>(
          Kg + ((size_t)bh * NTOK + nb + n) * 64 + k0);
      *reinterpret_cast<uint4*>(&kbf[(n * 64 + k0) ^ ((n & 7) << 3)]) = src;
    }
    __syncthreads();
    int nl = w * 16 + (lane & 15);
    short8 a0 = *reinterpret_cast<const short8*>(&kbf[(nl * 64 + ko) ^ ((nl & 7) << 3)]);
    short8 a1 = *reinterpret_cast<const short8*>(&kbf[(nl * 64 + ko + 32) ^ ((nl & 7) << 3)]);
#pragma unroll
    for (int mt = 0; mt < 17; ++mt) {
      int m = mt * 16 + (lane & 15);
      short8 b0 = *reinterpret_cast<const short8*>(&prjbf[(m * 64 + ko) ^ ((m & 7) << 3)]);
      short8 b1 = *reinterpret_cast<const short8*>(&prjbf[(m * 64 + ko + 32) ^ ((m & 7) << 3)]);
      f32x4 d = {0.f, 0.f, 0.f, 0.f};
      d = __builtin_amdgcn_mfma_f32_16x16x32_bf16(a0, b0, d, 0, 0, 0);
      d = __builtin_amdgcn_mfma_f32_16x16x32_bf16(a1, b1, d, 0, 0, 0);
      if (m < NBF) {
        mv = fmaxf(mv, fmaxf(fmaxf(d[0], d[1]), fmaxf(d[2], d[3])));
      }
    }
  }
  mv *= 0.35355339059327373f;
  for (int o = 32; o > 0; o >>= 1) mv = fmaxf(mv, __shfl_xor(mv, o));
  __syncthreads();
  if (lane == 0) red[w] = mv;
  __syncthreads();
  if (t == 0) {
    float m2 = fmaxf(fmaxf(red[0], red[1]), fmaxf(red[2], red[3]));
    unsigned int b = __float_as_uint(m2);
    unsigned int u = (b & 0x80000000u) ? ~b : (b | 0x80000000u);
    atomicMax(gmax, u);
  }
}

// ---------------- ctx = kp^T @ Vg, ksum = sum_n kp (MFMA) -------------------
__global__ __launch_bounds__(256) void k_ctx(
    const u16* __restrict__ Kg, const u16* __restrict__ Vg,
    const float* __restrict__ diagK, const float* __restrict__ proj,
    const unsigned int* __restrict__ gmax,
    float* __restrict__ ctx, float* __restrict__ ksum) {
  int bh = blockIdx.x, ns = blockIdx.y, mz = blockIdx.z;
  int m0 = mz * 144;
  int nmt = mz ? 8 : 9;
  int t = threadIdx.x, lane = t & 63, w = t >> 6;
  __shared__ __align__(16) u16 prjbf[144 * 64];
  __shared__ __align__(16) u16 kpT[144 * 64];
  __shared__ __align__(16) u16 kbf[64 * 64];
  __shared__ __align__(16) u16 vbT[64 * 64];
  __shared__ float dg[64];
  __shared__ float ksl[144];
  stage_prj(proj, prjbf, t, m0, 144);
  if (t < 144) ksl[t] = 0.f;
  unsigned int u = *gmax;
  unsigned int bb = (u & 0x80000000u) ? (u & 0x7FFFFFFFu) : ~u;
  float mx = __uint_as_float(bb);
  const float dn = 0.35355339059327373f;
  const float ratio = 1.0f / sqrtf(266.0f);
  int ko = (lane >> 4) * 8;
  f32x4 acc[9];
  float ksacc[9];
#pragma unroll
  for (int i = 0; i < 9; ++i) { acc[i] = (f32x4){0.f, 0.f, 0.f, 0.f}; ksacc[i] = 0.f; }

  for (int c4 = 0; c4 < 4; ++c4) {
    int nb = ns * 256 + c4 * 64;
    for (int p = 0; p < 2; ++p) {
      int idx = t + p * 256;
      int n = idx >> 3, k0 = (idx & 7) * 8;
      uint4 src = *reinterpret_cast<const uint4*>(
          Kg + ((size_t)bh * NTOK + nb + n) * 64 + k0);
      *reinterpret_cast<uint4*>(&kbf[(n * 64 + k0) ^ ((n & 7) << 3)]) = src;
      uint4 vv = *reinterpret_cast<const uint4*>(
          Vg + ((size_t)bh * NTOK + nb + n) * 64 + k0);
      u16 pv[8];
      *reinterpret_cast<uint4*>(pv) = vv;
#pragma unroll
      for (int i = 0; i < 8; ++i) {
        int d = k0 + i;
        vbT[(d * 64 + n) ^ ((d & 7) << 3)] = pv[i];
      }
    }
    if (t < 64) dg[t] = diagK[(size_t)bh * NTOK + nb + t];
    __syncthreads();
    {
      int nl = w * 16 + (lane & 15);
      short8 a0 = *reinterpret_cast<const short8*>(&kbf[(nl * 64 + ko) ^ ((nl & 7) << 3)]);
      short8 a1 = *reinterpret_cast<const short8*>(&kbf[(nl * 64 + ko + 32) ^ ((nl & 7) << 3)]);
      float dgv[4];
#pragma unroll
      for (int r = 0; r < 4; ++r) dgv[r] = dg[w * 16 + (lane >> 4) * 4 + r];
      int n0 = w * 16 + (lane >> 4) * 4;
#pragma unroll
      for (int mt = 0; mt < 9; ++mt) {
        if (mt < nmt) {
          int lr = mt * 16 + (lane & 15);
          short8 b0 = *reinterpret_cast<const short8*>(&prjbf[(lr * 64 + ko) ^ ((lr & 7) << 3)]);
          short8 b1 = *reinterpret_cast<const short8*>(&prjbf[(lr * 64 + ko + 32) ^ ((lr & 7) << 3)]);
          f32x4 d = {0.f, 0.f, 0.f, 0.f};
          d = __builtin_amdgcn_mfma_f32_16x16x32_bf16(a0, b0, d, 0, 0, 0);
          d = __builtin_amdgcn_mfma_f32_16x16x32_bf16(a1, b1, d, 0, 0, 0);
          float kp0 = ratio * (expf(dn * d[0] - dgv[0] - mx) + 1e-4f);
          float kp1 = ratio * (expf(dn * d[1] - dgv[1] - mx) + 1e-4f);
          float kp2 = ratio * (expf(dn * d[2] - dgv[2] - mx) + 1e-4f);
          float kp3 = ratio * (expf(dn * d[3] - dgv[3] - mx) + 1e-4f);
          ushort4 pkk;
          pkk.x = f2bf(kp0); pkk.y = f2bf(kp1); pkk.z = f2bf(kp2); pkk.w = f2bf(kp3);
          *reinterpret_cast<ushort4*>(&kpT[(lr * 64 + n0) ^ ((lr & 7) << 3)]) = pkk;
          float ksp = kp0 + kp1 + kp2 + kp3;
          ksp += __shfl_xor(ksp, 16);
          ksp += __shfl_xor(ksp, 32);
          ksacc[mt] += ksp;
        }
      }
    }
    __syncthreads();
    {
      int dcol = w * 16 + (lane & 15);
      short8 vb0 = *reinterpret_cast<const short8*>(&vbT[(dcol * 64 + ko) ^ ((dcol & 7) << 3)]);
      short8 vb1 = *reinterpret_cast<const short8*>(&vbT[(dcol * 64 + ko + 32) ^ ((dcol & 7) << 3)]);
#pragma unroll
      for (int mt = 0; mt < 9; ++mt) {
        if (mt < nmt) {
          int lr = mt * 16 + (lane & 15);
          short8 a0 = *reinterpret_cast<const short8*>(&kpT[(lr * 64 + ko) ^ ((lr & 7) << 3)]);
          short8 a1 = *reinterpret_cast<const short8*>(&kpT[(lr * 64 + ko + 32) ^ ((lr & 7) << 3)]);
          acc[mt] = __builtin_amdgcn_mfma_f32_16x16x32_bf16(a0, vb0, acc[mt], 0, 0, 0);
          acc[mt] = __builtin_amdgcn_mfma_f32_16x16x32_bf16(a1, vb1, acc[mt], 0, 0, 0);
        }
      }
    }
    __syncthreads();
  }
  int dcol = w * 16 + (lane & 15);
#pragma unroll
  for (int mt = 0; mt < 9; ++mt) {
    if (mt < nmt) {
#pragma unroll
      for (int r = 0; r < 4; ++r) {
        int m = m0 + mt * 16 + (lane >> 4) * 4 + r;
        if (m < NBF)
          atomicAdd(&ctx[((size_t)bh * NBF + m) * 64 + dcol], acc[mt][r]);
      }
      if (lane < 16) atomicAdd(&ksl[mt * 16 + lane], ksacc[mt]);
    }
  }
  __syncthreads();
  if (t < 144 && m0 + t < NBF)
    atomicAdd(&ksum[(size_t)bh * NBF + m0 + t], ksl[t]);
}

// ---------------- attention row 0, one block per (b, head) ------------------
__global__ __launch_bounds__(256) void k_att(
    const int* __restrict__ ids,
    const float* __restrict__ ln1g, const float* __restrict__ ln1b,
    const float* __restrict__ Wq, const float* __restrict__ Wk,
    const float* __restrict__ Wv, const float* __restrict__ proj,
    const u16* __restrict__ hng,
    const float* __restrict__ ctx, const float* __restrict__ ksum,
    const float* __restrict__ x0, float* __restrict__ att) {
  int b = blockIdx.x, h = blockIdx.y;
  int t = threadIdx.x;
  int lane = t & 63, wg = t >> 6;
  __shared__ float hn1[64], qh[64], qpart[4][64], red[4], pol[4][64];
  __shared__ float buf[272];
  __shared__ float dots[2048];
  __shared__ float wkq[64], svec[64];
  __shared__ u16 vst[512 * 64];
  const float dn = 0.35355339059327373f;
  const float ratio = 1.0f / sqrtf(266.0f);

  if (t < 64) {
    float xv = x0[b * 64 + t];
    float mu = wredsum64(xv) * 0.015625f;
    float dv = xv - mu;
    float var = wredsum64(dv * dv) * 0.015625f;
    hn1[t] = dv * rsqrtf(var + 1e-5f) * ln1g[t] + ln1b[t];
  }
  __syncthreads();
  {
    float p = 0;
#pragma unroll
    for (int dd = 0; dd < 16; ++dd)
      p += hn1[wg * 16 + dd] * Wq[(wg * 16 + dd) * 512 + h * 64 + lane];
    qpart[wg][lane] = p;
  }
  __syncthreads();
  if (t < 64) qh[t] = qpart[0][t] + qpart[1][t] + qpart[2][t] + qpart[3][t];
  __syncthreads();

  if (h < 4) {
    int bh = b * 4 + h;
    float dq = 0;
#pragma unroll
    for (int d = 0; d < 64; ++d) dq += qh[d] * qh[d];
    dq *= 0.0625f;
    float lmax = -3e38f;
#pragma unroll
    for (int pass = 0; pass < 2; ++pass) {
      int m = t + pass * 256;
      if (m < NBF) {
        const float4* pp = reinterpret_cast<const float4*>(proj + m * 64);
        float s = 0;
#pragma unroll
        for (int q4 = 0; q4 < 16; ++q4) {
          float4 uu = pp[q4];
          s += qh[q4 * 4] * uu.x + qh[q4 * 4 + 1] * uu.y +
               qh[q4 * 4 + 2] * uu.z + qh[q4 * 4 + 3] * uu.w;
        }
        float dash = dn * s;
        buf[m] = dash;
        lmax = fmaxf(lmax, dash);
      }
    }
    float mxq = bmax256(lmax, red);
    float part = 0;
#pragma unroll
    for (int pass = 0; pass < 2; ++pass) {
      int m = t + pass * 256;
      if (m < NBF) {
        float qp = ratio * (expf(buf[m] - dq - mxq) + 1e-4f);
        buf[m] = qp;
        part += qp * ksum[(size_t)bh * NBF + m];
      }
    }
    float den = bsum256(part, red);
    __syncthreads();
    {
      float s = 0;
      for (int m = wg; m < NBF; m += 4)
        s += buf[m] * ctx[((size_t)bh * NBF + m) * 64 + lane];
      pol[wg][lane] = s;
    }
    __syncthreads();
    if (t < 64)
      att[b * 512 + h * 64 + t] =
          (pol[0][t] + pol[1][t] + pol[2][t] + pol[3][t]) / den;
  } else {
    int ch = h * 64;
    if (t < 64) {
      float s = 0;
#pragma unroll 8
      for (int j = 0; j < 64; ++j) s += Wk[t * 512 + ch + j] * qh[j];
      wkq[t] = s;
    }
    __syncthreads();
    const u16* hnb = hng + (size_t)b * NTOK * 64;
    float lmax = -3e38f;
#pragma unroll
    for (int i = 0; i < 8; ++i) {
      int n1 = t + i * 256;
      const ushort4* hr = reinterpret_cast<const ushort4*>(hnb + (size_t)n1 * 64);
      float s = 0;
#pragma unroll
      for (int d4 = 0; d4 < 16; ++d4) {
        ushort4 uu = hr[d4];
        s += wkq[d4 * 4] * bf2f(uu.x) + wkq[d4 * 4 + 1] * bf2f(uu.y) +
             wkq[d4 * 4 + 2] * bf2f(uu.z) + wkq[d4 * 4 + 3] * bf2f(uu.w);
      }
      float dv = s * 0.125f;
      if (ids[b * NTOK + n1] == 0) dv = -1e9f;
      dots[n1] = dv;
      lmax = fmaxf(lmax, dv);
    }
    float mxl = bmax256(lmax, red);
    float ps = 0;
#pragma unroll
    for (int i = 0; i < 8; ++i) {
      int n1 = t + i * 256;
      float p = expf(dots[n1] - mxl);
      dots[n1] = p;
      ps += p;
    }
    float sden = bsum256(ps, red);
    float acc = 0;
    for (int c = 0; c < 4; ++c) {
      __syncthreads();
      const ushort4* src = reinterpret_cast<const ushort4*>(hnb + (size_t)(c * 512) * 64);
      ushort4* dst = reinterpret_cast<ushort4*>(vst);
#pragma unroll
      for (int i = 0; i < 32; ++i) dst[t + i * 256] = src[t + i * 256];
      __syncthreads();
      int r0 = wg * 128;
#pragma unroll 8
      for (int r = 0; r < 128; ++r)
        acc += dots[c * 512 + r0 + r] * bf2f(vst[(r0 + r) * 64 + lane]);
    }
    __syncthreads();
    pol[wg][lane] = acc;
    __syncthreads();
    if (t < 64) svec[t] = pol[0][t] + pol[1][t] + pol[2][t] + pol[3][t];
    __syncthreads();
    {
      float p2 = 0;
#pragma unroll
      for (int dd = 0; dd < 16; ++dd)
        p2 += svec[wg * 16 + dd] * Wv[(wg * 16 + dd) * 512 + ch + lane];
      pol[wg][lane] = p2;
    }
    __syncthreads();
    if (t < 64)
      att[b * 512 + h * 64 + t] =
          (pol[0][t] + pol[1][t] + pol[2][t] + pol[3][t]) / sden;
  }
}

// ---------------- tail at position 0: Wo, FF, final LN, heads ----------------
__global__ __launch_bounds__(256) void k_fin2(
    const float* __restrict__ ln2g, const float* __restrict__ ln2b,
    const float* __restrict__ Wo,
    const float* __restrict__ W1, const float* __restrict__ b1,
    const float* __restrict__ W2, const float* __restrict__ b2,
    const float* __restrict__ lnfg, const float* __restrict__ lnfb,
    const float* __restrict__ Wout, const float* __restrict__ bout,
    const float* __restrict__ Wc1, const float* __restrict__ bc1,
    const float* __restrict__ Wc2, const float* __restrict__ bc2,
    const float* __restrict__ x0, const float* __restrict__ att,
    float* __restrict__ out) {
  int b = blockIdx.x;
  int t = threadIdx.x;
  int lane = t & 63, wg = t >> 6;
  __shared__ float o512s[512], x0s[64], part[4][64];
  __shared__ float y1[64], hn2[64], gact[256], hfin[64], repS[64], c1s[32];
  o512s[t] = att[b * 512 + t];
  o512s[t + 256] = att[b * 512 + t + 256];
  if (t < 64) x0s[t] = x0[b * 64 + t];
  __syncthreads();
  {
    float s = 0;
#pragma unroll 4
    for (int c = wg * 128; c < wg * 128 + 128; ++c) s += o512s[c] * Wo[c * 64 + lane];
    part[wg][lane] = s;
  }
  __syncthreads();
  if (t < 64) {
    float yv = x0s[t] + part[0][t] + part[1][t] + part[2][t] + part[3][t];
    y1[t] = yv;
    float mu = wredsum64(yv) * 0.015625f;
    float dv = yv - mu;
    float var = wredsum64(dv * dv) * 0.015625f;
    hn2[t] = dv * rsqrtf(var + 1e-5f) * ln2g[t] + ln2b[t];
  }
  __syncthreads();
  {
    float s = b1[t];
#pragma unroll 4
    for (int d = 0; d < 64; ++d) s += hn2[d] * W1[d * 256 + t];
    gact[t] = 0.5f * s * (1.f + erff(s * 0.7071067811865475f));
  }
  __syncthreads();
  {
    float s = 0;
#pragma unroll 4
    for (int j = wg * 64; j < wg * 64 + 64; ++j) s += gact[j] * W2[j * 64 + lane];
    part[wg][lane] = s;
  }
  __syncthreads();
  if (t < 64) {
    float y2 = x0s[t] + b2[t] + part[0][t] + part[1][t] + part[2][t] + part[3][t];
    float hm = 0.5f * (y1[t] + y2);
    float mu = wredsum64(hm) * 0.015625f;
    float dv = hm - mu;
    float var = wredsum64(dv * dv) * 0.015625f;
    hfin[t] = dv * rsqrtf(var + 1e-5f) * lnfg[t] + lnfb[t];
  }
  __syncthreads();
  {
    float s = 0;
#pragma unroll
    for (int dd = 0; dd < 16; ++dd)
      s += hfin[wg * 16 + dd] * Wout[(wg * 16 + dd) * 64 + lane];
    part[wg][lane] = s;
  }
  __syncthreads();
  if (t < 64) {
    float s = bout[t] + part[0][t] + part[1][t] + part[2][t] + part[3][t];
    repS[t] = s;
    out[16 + b * 64 + t] = s;
  }
  __syncthreads();
  if (t < 32) {
    float s = bc1[t];
#pragma unroll 4
    for (int d = 0; d < 64; ++d) s += repS[d] * Wc1[d * 32 + t];
    c1s[t] = fmaxf(s, 0.f);
  }
  __syncthreads();
  if (t < 2) {
    float s = bc2[t];
#pragma unroll
    for (int jj = 0; jj < 32; ++jj) s += c1s[jj] * Wc2[jj * 2 + t];
    out[b * 2 + t] = s;
  }
}

extern "C" void kernel_launch(void* const* d_in, const int* in_sizes, int n_in,
                              void* d_out, int out_size, void* d_ws, size_t ws_size,
                              hipStream_t stream) {
  (void)in_sizes; (void)n_in; (void)out_size; (void)ws_size;
  const int* ids = (const int*)d_in[0];
  const float* tok = (const float*)d_in[1];
  const float* ln1g = (const float*)d_in[2];
  const float* ln1b = (const float*)d_in[3];
  const float* Wq = (const float*)d_in[4];
  const float* Wk = (const float*)d_in[5];
  const float* Wv = (const float*)d_in[6];
  const float* Wo = (const float*)d_in[7];
  const float* ln2g = (const float*)d_in[8];
  const float* ln2b = (const float*)d_in[9];
  const float* W1 = (const float*)d_in[10];
  const float* b1 = (const float*)d_in[11];
  const float* W2 = (const float*)d_in[12];
  const float* b2 = (const float*)d_in[13];
  const float* lnfg = (const float*)d_in[14];
  const float* lnfb = (const float*)d_in[15];
  const float* Wout = (const float*)d_in[16];
  const float* bout = (const float*)d_in[17];
  const float* Wc1 = (const float*)d_in[18];
  const float* bc1 = (const float*)d_in[19];
  const float* Wc2 = (const float*)d_in[20];
  const float* bc2 = (const float*)d_in[21];
  const float* proj = (const float*)d_in[22];

  uint8_t* w = (uint8_t*)d_ws;
  size_t off = 0;
  const size_t big = (size_t)8 * 4 * NTOK * 64 * 2;  // 4.19 MB each
  u16* Kg = (u16*)(w + off); off += big;
  u16* Vg = (u16*)(w + off); off += big;
  u16* hng = (u16*)(w + off); off += (size_t)8 * NTOK * 64 * 2;  // 2 MB
  float* diagK = (float*)(w + off); off += (size_t)8 * 4 * NTOK * 4;
  float* ctx = (float*)(w + off); off += (size_t)8 * 4 * NBF * 64 * 4;
  float* ksum = (float*)(w + off); off += (size_t)8 * 4 * NBF * 4;
  unsigned int* gmax = (unsigned int*)(w + off); off += 4;
  off += 12;  // pad so the zero region (ctx..gmax) is a whole uint4 count
  float* x0 = (float*)(w + off); off += 64 * 8 * 4;
  float* att = (float*)(w + off); off += (size_t)8 * 512 * 4;
  float2* sc = (float2*)(w + off); off += (size_t)NTOK * 32 * 8;  // 512 KB

  k_tab<<<256, 256, 0, stream>>>(sc);
  k_prep<<<8 * 256, 128, 0, stream>>>(ids, tok, ln1g, ln1b, Wk, Wv, sc, Kg, Vg,
                                      hng, diagK, x0, (uint4*)ctx);
  k_max<<<dim3(32, 16), 256, 0, stream>>>(Kg, proj, gmax);
  k_ctx<<<dim3(32, 8, 2), 256, 0, stream>>>(Kg, Vg, diagK, proj, gmax, ctx, ksum);
  k_att<<<dim3(8, 8), 256, 0, stream>>>(ids, ln1g, ln1b, Wq, Wk, Wv, proj, hng,
                                        ctx, ksum, x0, att);
  k_fin2<<<8, 256, 0, stream>>>(ln2g, ln2b, Wo, W1, b1, W2, b2, lnfg, lnfb, Wout,
                                bout, Wc1, bc1, Wc2, bc2, x0, att, (float*)d_out);
}

// Round 13
// 115.151 us; speedup vs baseline: 1.2824x; 1.0391x over previous
//
#include <hip/hip_runtime.h>
#include <math.h>

#define NTOK 2048
#define NBF 266
#define MPAD 272
// zero region: ctx + ksum + gmax(4) + cnt(32) + pad(12)
#define ZWORDS4 138323u   // (2179072 + 34048 + 48) / 16

typedef unsigned short u16;
typedef __attribute__((ext_vector_type(8))) short short8;
typedef __attribute__((ext_vector_type(4))) float f32x4;

__device__ __forceinline__ float bf2f(u16 u) {
  unsigned int x = ((unsigned int)u) << 16;
  return __uint_as_float(x);
}
__device__ __forceinline__ u16 f2bf(float f) {
  unsigned int x = __float_as_uint(f);
  unsigned int r = x + 0x7FFFu + ((x >> 16) & 1u);
  return (u16)(r >> 16);
}
__device__ __forceinline__ float wredsum64(float v) {
  for (int o = 32; o > 0; o >>= 1) v += __shfl_xor(v, o);
  return v;
}
__device__ __forceinline__ float bsum256(float v, float* red) {
  for (int o = 32; o > 0; o >>= 1) v += __shfl_xor(v, o);
  __syncthreads();
  if ((threadIdx.x & 63) == 0) red[threadIdx.x >> 6] = v;
  __syncthreads();
  return red[0] + red[1] + red[2] + red[3];
}
__device__ __forceinline__ float bmax256(float v, float* red) {
  for (int o = 32; o > 0; o >>= 1) v = fmaxf(v, __shfl_xor(v, o));
  __syncthreads();
  if ((threadIdx.x & 63) == 0) red[threadIdx.x >> 6] = v;
  __syncthreads();
  return fmaxf(fmaxf(red[0], red[1]), fmaxf(red[2], red[3]));
}
#define INVF_C 0.4152410118609190f

// ---- prep v6: 128 thr / 8 tok / 4 cols; in-block LDS trig table ------------
__global__ __launch_bounds__(128) void k_prep(
    const int* __restrict__ ids, const float* __restrict__ tok_emb,
    const float* __restrict__ ln1g, const float* __restrict__ ln1b,
    const float* __restrict__ Wk, const float* __restrict__ Wv,
    u16* __restrict__ Kg, u16* __restrict__ Vg, u16* __restrict__ hng,
    float* __restrict__ diagK, float* __restrict__ x0,
    uint4* __restrict__ zbase) {
  int blk = blockIdx.x;            // 8 * 256 blocks
  int b = blk >> 8, nt = blk & 255;
  int n0 = nt * 8;
  int t = threadIdx.x;             // 0..127
  int w = t >> 6, lane = t & 63;
  __shared__ float hn[8][64];
  __shared__ float idm[8];
  __shared__ float2 sctab[256];    // [tok 0..7][freq 0..31]

  // fused zeroing of ctx/ksum/gmax/cnt (must re-zero every call)
  {
    unsigned int zi = (unsigned int)blk * 128u + (unsigned int)t;
    if (zi < ZWORDS4) zbase[zi] = make_uint4(0u, 0u, 0u, 0u);
  }
  // in-block trig table: 2 entries/thread (identical op order to before)
#pragma unroll
  for (int p = 0; p < 2; ++p) {
    int ee = t + p * 128;
    int n = n0 + (ee >> 5), i = ee & 31;
    float ang = (float)n * exp2f(-INVF_C * (float)i);
    sctab[ee] = make_float2(sinf(ang), cosf(ang));
  }
  __syncthreads();

  // LN: wave w handles tokens w*4 .. w*4+3; posenc from LDS table
  float g = ln1g[lane], bb = ln1b[lane];
#pragma unroll
  for (int j2 = 0; j2 < 4; ++j2) {
    int j = w * 4 + j2;
    int n = n0 + j;
    int id = ids[b * NTOK + n];
    float2 p = sctab[(j << 5) + (lane & 31)];
    float pv = (lane < 32) ? p.x : p.y;
    float xv = tok_emb[id * 64 + lane] + pv;
    float mu = wredsum64(xv) * 0.015625f;
    float dv = xv - mu;
    float var = wredsum64(dv * dv) * 0.015625f;
    float hv = dv * rsqrtf(var + 1e-5f) * g + bb;
    hn[j][lane] = hv;
    hng[((size_t)b * NTOK + n) * 64 + lane] = f2bf(hv);
    if (lane == 0) idm[j] = (id != 0) ? 1.f : 0.f;
    if (n == 0) x0[b * 64 + lane] = xv;
  }
  __syncthreads();

  // GEMM: thread t covers 4 global-head output cols
  float acc[8][4];
#pragma unroll
  for (int j = 0; j < 8; ++j)
#pragma unroll
    for (int i = 0; i < 4; ++i) acc[j][i] = 0.f;
  const float* wsrc = (t < 64) ? (Wk + t * 4) : (Wv + (t - 64) * 4);
  for (int d2 = 0; d2 < 64; ++d2) {
    float4 w0 = *reinterpret_cast<const float4*>(wsrc + d2 * 512);
#pragma unroll
    for (int j = 0; j < 8; ++j) {
      float hv = hn[j][d2];
      acc[j][0] += hv * w0.x; acc[j][1] += hv * w0.y;
      acc[j][2] += hv * w0.z; acc[j][3] += hv * w0.w;
    }
  }

  if (t < 64) {   // K-global: rotary (table), diag, write Kg
    int hh = t >> 4, db = (t & 15) * 4;
    int i0 = (t & 15) * 2;
#pragma unroll
    for (int j = 0; j < 8; ++j) {
      int n = n0 + j;
      float2 t0 = sctab[(j << 5) + i0];
      float2 t1 = sctab[(j << 5) + i0 + 1];
      float s0 = t0.x, c0 = t0.y, s1 = t1.x, c1 = t1.y;
      float kr0 = acc[j][0] * c0 - acc[j][1] * s0;
      float kr1 = acc[j][1] * c0 + acc[j][0] * s0;
      float kr2 = acc[j][2] * c1 - acc[j][3] * s1;
      float kr3 = acc[j][3] * c1 + acc[j][2] * s1;
      float dq = kr0 * kr0 + kr1 * kr1 + kr2 * kr2 + kr3 * kr3;
      dq += __shfl_xor(dq, 1);
      dq += __shfl_xor(dq, 2);
      dq += __shfl_xor(dq, 4);
      dq += __shfl_xor(dq, 8);   // 16-thread head group
      size_t hb = (size_t)(b * 4 + hh) * NTOK + n;
      if ((t & 15) == 0) diagK[hb] = dq * 0.0625f;  // 0.5*dn*dn = 1/16
      ushort4 s;
      s.x = f2bf(kr0); s.y = f2bf(kr1); s.z = f2bf(kr2); s.w = f2bf(kr3);
      *reinterpret_cast<ushort4*>(Kg + hb * 64 + db) = s;
    }
  } else {        // V-global: mask, write Vg
    int tv = t - 64;
    int hh = tv >> 4, db = (tv & 15) * 4;
#pragma unroll
    for (int j = 0; j < 8; ++j) {
      int n = n0 + j;
      float m = idm[j];
      ushort4 vv;
      vv.x = f2bf(acc[j][0] * m); vv.y = f2bf(acc[j][1] * m);
      vv.z = f2bf(acc[j][2] * m); vv.w = f2bf(acc[j][3] * m);
      *reinterpret_cast<ushort4*>(
          Vg + ((size_t)(b * 4 + hh) * NTOK + n) * 64 + db) = vv;
    }
  }
}

// ---- stage proj rows [m0, m0+rows) into swizzled bf16 LDS [rows][64] -------
__device__ __forceinline__ void stage_prj(const float* __restrict__ proj,
                                          u16* prjbf, int t, int m0, int rows) {
  for (int c = t; c < rows * 8; c += 256) {
    int r = c >> 3, k0 = (c & 7) * 8;
    int m = m0 + r;
    int e = (r * 64 + k0) ^ ((r & 7) << 3);
    uint4 pk;
    if (m < NBF) {
      const float4* ps = reinterpret_cast<const float4*>(proj + m * 64 + k0);
      float4 p0 = ps[0], p1 = ps[1];
      pk.x = (unsigned)f2bf(p0.x) | ((unsigned)f2bf(p0.y) << 16);
      pk.y = (unsigned)f2bf(p0.z) | ((unsigned)f2bf(p0.w) << 16);
      pk.z = (unsigned)f2bf(p1.x) | ((unsigned)f2bf(p1.y) << 16);
      pk.w = (unsigned)f2bf(p1.z) | ((unsigned)f2bf(p1.w) << 16);
    } else {
      pk.x = pk.y = pk.z = pk.w = 0u;
    }
    *reinterpret_cast<uint4*>(&prjbf[e]) = pk;
  }
}

// ---------------- global max over dash = dn * Kg @ proj^T (MFMA) ------------
__global__ __launch_bounds__(256) void k_max(
    const u16* __restrict__ Kg, const float* __restrict__ proj,
    unsigned int* __restrict__ gmax) {
  int bh = blockIdx.x, ns = blockIdx.y;
  int t = threadIdx.x, lane = t & 63, w = t >> 6;
  __shared__ __align__(16) u16 prjbf[MPAD * 64];
  __shared__ __align__(16) u16 kbf[64 * 64];
  __shared__ float red[4];
  stage_prj(proj, prjbf, t, 0, MPAD);
  float mv = -3e38f;
  int ko = (lane >> 4) * 8;
  for (int c4 = 0; c4 < 2; ++c4) {
    int nb = ns * 128 + c4 * 64;
    __syncthreads();
    for (int p = 0; p < 2; ++p) {
      int idx = t + p * 256;
      int n = idx >> 3, k0 = (idx & 7) * 8;
      uint4 src = *reinterpret_cast<const uint4*>(
          Kg + ((size_t)bh * NTOK + nb + n) * 64 + k0);
      *reinterpret_cast<uint4*>(&kbf[(n * 64 + k0) ^ ((n & 7) << 3)]) = src;
    }
    __syncthreads();
    int nl = w * 16 + (lane & 15);
    short8 a0 = *reinterpret_cast<const short8*>(&kbf[(nl * 64 + ko) ^ ((nl & 7) << 3)]);
    short8 a1 = *reinterpret_cast<const short8*>(&kbf[(nl * 64 + ko + 32) ^ ((nl & 7) << 3)]);
#pragma unroll
    for (int mt = 0; mt < 17; ++mt) {
      int m = mt * 16 + (lane & 15);
      short8 b0 = *reinterpret_cast<const short8*>(&prjbf[(m * 64 + ko) ^ ((m & 7) << 3)]);
      short8 b1 = *reinterpret_cast<const short8*>(&prjbf[(m * 64 + ko + 32) ^ ((m & 7) << 3)]);
      f32x4 d = {0.f, 0.f, 0.f, 0.f};
      d = __builtin_amdgcn_mfma_f32_16x16x32_bf16(a0, b0, d, 0, 0, 0);
      d = __builtin_amdgcn_mfma_f32_16x16x32_bf16(a1, b1, d, 0, 0, 0);
      if (m < NBF) {
        mv = fmaxf(mv, fmaxf(fmaxf(d[0], d[1]), fmaxf(d[2], d[3])));
      }
    }
  }
  mv *= 0.35355339059327373f;
  for (int o = 32; o > 0; o >>= 1) mv = fmaxf(mv, __shfl_xor(mv, o));
  __syncthreads();
  if (lane == 0) red[w] = mv;
  __syncthreads();
  if (t == 0) {
    float m2 = fmaxf(fmaxf(red[0], red[1]), fmaxf(red[2], red[3]));
    unsigned int b = __float_as_uint(m2);
    unsigned int u = (b & 0x80000000u) ? ~b : (b | 0x80000000u);
    atomicMax(gmax, u);
  }
}

// ---------------- ctx = kp^T @ Vg, ksum = sum_n kp (MFMA) -------------------
__global__ __launch_bounds__(256) void k_ctx(
    const u16* __restrict__ Kg, const u16* __restrict__ Vg,
    const float* __restrict__ diagK, const float* __restrict__ proj,
    const unsigned int* __restrict__ gmax,
    float* __restrict__ ctx, float* __restrict__ ksum) {
  int bh = blockIdx.x, ns = blockIdx.y, mz = blockIdx.z;
  int m0 = mz * 144;
  int nmt = mz ? 8 : 9;
  int t = threadIdx.x, lane = t & 63, w = t >> 6;
  __shared__ __align__(16) u16 prjbf[144 * 64];
  __shared__ __align__(16) u16 kpT[144 * 64];
  __shared__ __align__(16) u16 kbf[64 * 64];
  __shared__ __align__(16) u16 vbT[64 * 64];
  __shared__ float dg[64];
  __shared__ float ksl[144];
  stage_prj(proj, prjbf, t, m0, 144);
  if (t < 144) ksl[t] = 0.f;
  unsigned int u = *gmax;
  unsigned int bb = (u & 0x80000000u) ? (u & 0x7FFFFFFFu) : ~u;
  float mx = __uint_as_float(bb);
  const float dn = 0.35355339059327373f;
  const float ratio = 1.0f / sqrtf(266.0f);
  int ko = (lane >> 4) * 8;
  f32x4 acc[9];
  float ksacc[9];
#pragma unroll
  for (int i = 0; i < 9; ++i) { acc[i] = (f32x4){0.f, 0.f, 0.f, 0.f}; ksacc[i] = 0.f; }

  for (int c4 = 0; c4 < 4; ++c4) {
    int nb = ns * 256 + c4 * 64;
    for (int p = 0; p < 2; ++p) {
      int idx = t + p * 256;
      int n = idx >> 3, k0 = (idx & 7) * 8;
      uint4 src = *reinterpret_cast<const uint4*>(
          Kg + ((size_t)bh * NTOK + nb + n) * 64 + k0);
      *reinterpret_cast<uint4*>(&kbf[(n * 64 + k0) ^ ((n & 7) << 3)]) = src;
      uint4 vv = *reinterpret_cast<const uint4*>(
          Vg + ((size_t)bh * NTOK + nb + n) * 64 + k0);
      u16 pv[8];
      *reinterpret_cast<uint4*>(pv) = vv;
#pragma unroll
      for (int i = 0; i < 8; ++i) {
        int d = k0 + i;
        vbT[(d * 64 + n) ^ ((d & 7) << 3)] = pv[i];
      }
    }
    if (t < 64) dg[t] = diagK[(size_t)bh * NTOK + nb + t];
    __syncthreads();
    {
      int nl = w * 16 + (lane & 15);
      short8 a0 = *reinterpret_cast<const short8*>(&kbf[(nl * 64 + ko) ^ ((nl & 7) << 3)]);
      short8 a1 = *reinterpret_cast<const short8*>(&kbf[(nl * 64 + ko + 32) ^ ((nl & 7) << 3)]);
      float dgv[4];
#pragma unroll
      for (int r = 0; r < 4; ++r) dgv[r] = dg[w * 16 + (lane >> 4) * 4 + r];
      int n0 = w * 16 + (lane >> 4) * 4;
#pragma unroll
      for (int mt = 0; mt < 9; ++mt) {
        if (mt < nmt) {
          int lr = mt * 16 + (lane & 15);
          short8 b0 = *reinterpret_cast<const short8*>(&prjbf[(lr * 64 + ko) ^ ((lr & 7) << 3)]);
          short8 b1 = *reinterpret_cast<const short8*>(&prjbf[(lr * 64 + ko + 32) ^ ((lr & 7) << 3)]);
          f32x4 d = {0.f, 0.f, 0.f, 0.f};
          d = __builtin_amdgcn_mfma_f32_16x16x32_bf16(a0, b0, d, 0, 0, 0);
          d = __builtin_amdgcn_mfma_f32_16x16x32_bf16(a1, b1, d, 0, 0, 0);
          float kp0 = ratio * (expf(dn * d[0] - dgv[0] - mx) + 1e-4f);
          float kp1 = ratio * (expf(dn * d[1] - dgv[1] - mx) + 1e-4f);
          float kp2 = ratio * (expf(dn * d[2] - dgv[2] - mx) + 1e-4f);
          float kp3 = ratio * (expf(dn * d[3] - dgv[3] - mx) + 1e-4f);
          ushort4 pkk;
          pkk.x = f2bf(kp0); pkk.y = f2bf(kp1); pkk.z = f2bf(kp2); pkk.w = f2bf(kp3);
          *reinterpret_cast<ushort4*>(&kpT[(lr * 64 + n0) ^ ((lr & 7) << 3)]) = pkk;
          float ksp = kp0 + kp1 + kp2 + kp3;
          ksp += __shfl_xor(ksp, 16);
          ksp += __shfl_xor(ksp, 32);
          ksacc[mt] += ksp;
        }
      }
    }
    __syncthreads();
    {
      int dcol = w * 16 + (lane & 15);
      short8 vb0 = *reinterpret_cast<const short8*>(&vbT[(dcol * 64 + ko) ^ ((dcol & 7) << 3)]);
      short8 vb1 = *reinterpret_cast<const short8*>(&vbT[(dcol * 64 + ko + 32) ^ ((dcol & 7) << 3)]);
#pragma unroll
      for (int mt = 0; mt < 9; ++mt) {
        if (mt < nmt) {
          int lr = mt * 16 + (lane & 15);
          short8 a0 = *reinterpret_cast<const short8*>(&kpT[(lr * 64 + ko) ^ ((lr & 7) << 3)]);
          short8 a1 = *reinterpret_cast<const short8*>(&kpT[(lr * 64 + ko + 32) ^ ((lr & 7) << 3)]);
          acc[mt] = __builtin_amdgcn_mfma_f32_16x16x32_bf16(a0, vb0, acc[mt], 0, 0, 0);
          acc[mt] = __builtin_amdgcn_mfma_f32_16x16x32_bf16(a1, vb1, acc[mt], 0, 0, 0);
        }
      }
    }
    __syncthreads();
  }
  int dcol = w * 16 + (lane & 15);
#pragma unroll
  for (int mt = 0; mt < 9; ++mt) {
    if (mt < nmt) {
#pragma unroll
      for (int r = 0; r < 4; ++r) {
        int m = m0 + mt * 16 + (lane >> 4) * 4 + r;
        if (m < NBF)
          atomicAdd(&ctx[((size_t)bh * NBF + m) * 64 + dcol], acc[mt][r]);
      }
      if (lane < 16) atomicAdd(&ksl[mt * 16 + lane], ksacc[mt]);
    }
  }
  __syncthreads();
  if (t < 144 && m0 + t < NBF)
    atomicAdd(&ksum[(size_t)bh * NBF + m0 + t], ksl[t]);
}

// ---- attention row 0 per (b,head); LAST block per b runs the tail ----------
__global__ __launch_bounds__(256) void k_att(
    const int* __restrict__ ids,
    const float* __restrict__ ln1g, const float* __restrict__ ln1b,
    const float* __restrict__ Wq, const float* __restrict__ Wk,
    const float* __restrict__ Wv, const float* __restrict__ proj,
    const u16* __restrict__ hng,
    const float* __restrict__ ctx, const float* __restrict__ ksum,
    const float* __restrict__ x0,
    const float* __restrict__ ln2g, const float* __restrict__ ln2b,
    const float* __restrict__ Wo,
    const float* __restrict__ W1, const float* __restrict__ b1,
    const float* __restrict__ W2, const float* __restrict__ b2,
    const float* __restrict__ lnfg, const float* __restrict__ lnfb,
    const float* __restrict__ Wout, const float* __restrict__ bout,
    const float* __restrict__ Wc1, const float* __restrict__ bc1,
    const float* __restrict__ Wc2, const float* __restrict__ bc2,
    float* __restrict__ att, unsigned int* __restrict__ cnt,
    float* __restrict__ out) {
  int b = blockIdx.x, h = blockIdx.y;
  int t = threadIdx.x;
  int lane = t & 63, wg = t >> 6;
  __shared__ float hn1[64], qh[64], qpart[4][64], red[4], pol[4][64];
  __shared__ float buf[272];
  __shared__ float dots[2048];
  __shared__ float wkq[64], svec[64];
  __shared__ u16 vst[512 * 64];
  __shared__ int lastf;
  // tail arrays
  __shared__ float fo512[512], fx0[64], fy1[64], fhn2[64], fgact[256];
  __shared__ float fhfin[64], frep[64], fc1[32];
  const float dn = 0.35355339059327373f;
  const float ratio = 1.0f / sqrtf(266.0f);

  if (t < 64) {
    float xv = x0[b * 64 + t];
    float mu = wredsum64(xv) * 0.015625f;
    float dv = xv - mu;
    float var = wredsum64(dv * dv) * 0.015625f;
    hn1[t] = dv * rsqrtf(var + 1e-5f) * ln1g[t] + ln1b[t];
  }
  __syncthreads();
  {
    float p = 0;
#pragma unroll
    for (int dd = 0; dd < 16; ++dd)
      p += hn1[wg * 16 + dd] * Wq[(wg * 16 + dd) * 512 + h * 64 + lane];
    qpart[wg][lane] = p;
  }
  __syncthreads();
  if (t < 64) qh[t] = qpart[0][t] + qpart[1][t] + qpart[2][t] + qpart[3][t];
  __syncthreads();

  if (h < 4) {
    int bh = b * 4 + h;
    float dq = 0;
#pragma unroll
    for (int d = 0; d < 64; ++d) dq += qh[d] * qh[d];
    dq *= 0.0625f;
    float lmax = -3e38f;
#pragma unroll
    for (int pass = 0; pass < 2; ++pass) {
      int m = t + pass * 256;
      if (m < NBF) {
        const float4* pp = reinterpret_cast<const float4*>(proj + m * 64);
        float s = 0;
#pragma unroll
        for (int q4 = 0; q4 < 16; ++q4) {
          float4 uu = pp[q4];
          s += qh[q4 * 4] * uu.x + qh[q4 * 4 + 1] * uu.y +
               qh[q4 * 4 + 2] * uu.z + qh[q4 * 4 + 3] * uu.w;
        }
        float dash = dn * s;
        buf[m] = dash;
        lmax = fmaxf(lmax, dash);
      }
    }
    float mxq = bmax256(lmax, red);
    float part = 0;
#pragma unroll
    for (int pass = 0; pass < 2; ++pass) {
      int m = t + pass * 256;
      if (m < NBF) {
        float qp = ratio * (expf(buf[m] - dq - mxq) + 1e-4f);
        buf[m] = qp;
        part += qp * ksum[(size_t)bh * NBF + m];
      }
    }
    float den = bsum256(part, red);
    __syncthreads();
    {
      float s = 0;
      for (int m = wg; m < NBF; m += 4)
        s += buf[m] * ctx[((size_t)bh * NBF + m) * 64 + lane];
      pol[wg][lane] = s;
    }
    __syncthreads();
    if (t < 64)
      att[b * 512 + h * 64 + t] =
          (pol[0][t] + pol[1][t] + pol[2][t] + pol[3][t]) / den;
  } else {
    int ch = h * 64;
    if (t < 64) {
      float s = 0;
#pragma unroll 8
      for (int j = 0; j < 64; ++j) s += Wk[t * 512 + ch + j] * qh[j];
      wkq[t] = s;
    }
    __syncthreads();
    const u16* hnb = hng + (size_t)b * NTOK * 64;
    float lmax = -3e38f;
#pragma unroll
    for (int i = 0; i < 8; ++i) {
      int n1 = t + i * 256;
      const ushort4* hr = reinterpret_cast<const ushort4*>(hnb + (size_t)n1 * 64);
      float s = 0;
#pragma unroll
      for (int d4 = 0; d4 < 16; ++d4) {
        ushort4 uu = hr[d4];
        s += wkq[d4 * 4] * bf2f(uu.x) + wkq[d4 * 4 + 1] * bf2f(uu.y) +
             wkq[d4 * 4 + 2] * bf2f(uu.z) + wkq[d4 * 4 + 3] * bf2f(uu.w);
      }
      float dv = s * 0.125f;
      if (ids[b * NTOK + n1] == 0) dv = -1e9f;
      dots[n1] = dv;
      lmax = fmaxf(lmax, dv);
    }
    float mxl = bmax256(lmax, red);
    float ps = 0;
#pragma unroll
    for (int i = 0; i < 8; ++i) {
      int n1 = t + i * 256;
      float p = expf(dots[n1] - mxl);
      dots[n1] = p;
      ps += p;
    }
    float sden = bsum256(ps, red);
    float acc = 0;
    for (int c = 0; c < 4; ++c) {
      __syncthreads();
      const ushort4* src = reinterpret_cast<const ushort4*>(hnb + (size_t)(c * 512) * 64);
      ushort4* dst = reinterpret_cast<ushort4*>(vst);
#pragma unroll
      for (int i = 0; i < 32; ++i) dst[t + i * 256] = src[t + i * 256];
      __syncthreads();
      int r0 = wg * 128;
#pragma unroll 8
      for (int r = 0; r < 128; ++r)
        acc += dots[c * 512 + r0 + r] * bf2f(vst[(r0 + r) * 64 + lane]);
    }
    __syncthreads();
    pol[wg][lane] = acc;
    __syncthreads();
    if (t < 64) svec[t] = pol[0][t] + pol[1][t] + pol[2][t] + pol[3][t];
    __syncthreads();
    {
      float p2 = 0;
#pragma unroll
      for (int dd = 0; dd < 16; ++dd)
        p2 += svec[wg * 16 + dd] * Wv[(wg * 16 + dd) * 512 + ch + lane];
      pol[wg][lane] = p2;
    }
    __syncthreads();
    if (t < 64)
      att[b * 512 + h * 64 + t] =
          (pol[0][t] + pol[1][t] + pol[2][t] + pol[3][t]) / sden;
  }

  // ---- completion count: last block for this b runs the tail ----
  __syncthreads();
  if (t == 0) {
    __threadfence();                                  // release att stores
    unsigned int prev = atomicAdd(&cnt[b], 1u);       // device-scope
    lastf = (prev == 7u) ? 1 : 0;
  }
  __syncthreads();
  if (!lastf) return;
  __threadfence();                                    // acquire others' att

  fo512[t] = att[b * 512 + t];
  fo512[t + 256] = att[b * 512 + t + 256];
  if (t < 64) fx0[t] = x0[b * 64 + t];
  __syncthreads();
  {
    float s = 0;
#pragma unroll 4
    for (int c = wg * 128; c < wg * 128 + 128; ++c) s += fo512[c] * Wo[c * 64 + lane];
    pol[wg][lane] = s;
  }
  __syncthreads();
  if (t < 64) {
    float yv = fx0[t] + pol[0][t] + pol[1][t] + pol[2][t] + pol[3][t];
    fy1[t] = yv;
    float mu = wredsum64(yv) * 0.015625f;
    float dv = yv - mu;
    float var = wredsum64(dv * dv) * 0.015625f;
    fhn2[t] = dv * rsqrtf(var + 1e-5f) * ln2g[t] + ln2b[t];
  }
  __syncthreads();
  {
    float s = b1[t];
#pragma unroll 4
    for (int d = 0; d < 64; ++d) s += fhn2[d] * W1[d * 256 + t];
    fgact[t] = 0.5f * s * (1.f + erff(s * 0.7071067811865475f));
  }
  __syncthreads();
  {
    float s = 0;
#pragma unroll 4
    for (int j = wg * 64; j < wg * 64 + 64; ++j) s += fgact[j] * W2[j * 64 + lane];
    pol[wg][lane] = s;
  }
  __syncthreads();
  if (t < 64) {
    float y2 = fx0[t] + b2[t] + pol[0][t] + pol[1][t] + pol[2][t] + pol[3][t];
    float hm = 0.5f * (fy1[t] + y2);
    float mu = wredsum64(hm) * 0.015625f;
    float dv = hm - mu;
    float var = wredsum64(dv * dv) * 0.015625f;
    fhfin[t] = dv * rsqrtf(var + 1e-5f) * lnfg[t] + lnfb[t];
  }
  __syncthreads();
  {
    float s = 0;
#pragma unroll
    for (int dd = 0; dd < 16; ++dd)
      s += fhfin[wg * 16 + dd] * Wout[(wg * 16 + dd) * 64 + lane];
    pol[wg][lane] = s;
  }
  __syncthreads();
  if (t < 64) {
    float s = bout[t] + pol[0][t] + pol[1][t] + pol[2][t] + pol[3][t];
    frep[t] = s;
    out[16 + b * 64 + t] = s;
  }
  __syncthreads();
  if (t < 32) {
    float s = bc1[t];
#pragma unroll 4
    for (int d = 0; d < 64; ++d) s += frep[d] * Wc1[d * 32 + t];
    fc1[t] = fmaxf(s, 0.f);
  }
  __syncthreads();
  if (t < 2) {
    float s = bc2[t];
#pragma unroll
    for (int jj = 0; jj < 32; ++jj) s += fc1[jj] * Wc2[jj * 2 + t];
    out[b * 2 + t] = s;
  }
}

extern "C" void kernel_launch(void* const* d_in, const int* in_sizes, int n_in,
                              void* d_out, int out_size, void* d_ws, size_t ws_size,
                              hipStream_t stream) {
  (void)in_sizes; (void)n_in; (void)out_size; (void)ws_size;
  const int* ids = (const int*)d_in[0];
  const float* tok = (const float*)d_in[1];
  const float* ln1g = (const float*)d_in[2];
  const float* ln1b = (const float*)d_in[3];
  const float* Wq = (const float*)d_in[4];
  const float* Wk = (const float*)d_in[5];
  const float* Wv = (const float*)d_in[6];
  const float* Wo = (const float*)d_in[7];
  const float* ln2g = (const float*)d_in[8];
  const float* ln2b = (const float*)d_in[9];
  const float* W1 = (const float*)d_in[10];
  const float* b1 = (const float*)d_in[11];
  const float* W2 = (const float*)d_in[12];
  const float* b2 = (const float*)d_in[13];
  const float* lnfg = (const float*)d_in[14];
  const float* lnfb = (const float*)d_in[15];
  const float* Wout = (const float*)d_in[16];
  const float* bout = (const float*)d_in[17];
  const float* Wc1 = (const float*)d_in[18];
  const float* bc1 = (const float*)d_in[19];
  const float* Wc2 = (const float*)d_in[20];
  const float* bc2 = (const float*)d_in[21];
  const float* proj = (const float*)d_in[22];

  uint8_t* w = (uint8_t*)d_ws;
  size_t off = 0;
  const size_t big = (size_t)8 * 4 * NTOK * 64 * 2;  // 8.39 MB each
  u16* Kg = (u16*)(w + off); off += big;
  u16* Vg = (u16*)(w + off); off += big;
  u16* hng = (u16*)(w + off); off += (size_t)8 * NTOK * 64 * 2;  // 2 MB
  float* diagK = (float*)(w + off); off += (size_t)8 * 4 * NTOK * 4;
  float* ctx = (float*)(w + off); off += (size_t)8 * 4 * NBF * 64 * 4;
  float* ksum = (float*)(w + off); off += (size_t)8 * 4 * NBF * 4;
  unsigned int* gmax = (unsigned int*)(w + off); off += 4;
  unsigned int* cnt = (unsigned int*)(w + off); off += 32;
  off += 12;  // pad so the zero region (ctx..cnt) is a whole uint4 count
  float* x0 = (float*)(w + off); off += 64 * 8 * 4;
  float* att = (float*)(w + off); off += (size_t)8 * 512 * 4;

  k_prep<<<8 * 256, 128, 0, stream>>>(ids, tok, ln1g, ln1b, Wk, Wv, Kg, Vg, hng,
                                      diagK, x0, (uint4*)ctx);
  k_max<<<dim3(32, 16), 256, 0, stream>>>(Kg, proj, gmax);
  k_ctx<<<dim3(32, 8, 2), 256, 0, stream>>>(Kg, Vg, diagK, proj, gmax, ctx, ksum);
  k_att<<<dim3(8, 8), 256, 0, stream>>>(ids, ln1g, ln1b, Wq, Wk, Wv, proj, hng,
                                        ctx, ksum, x0, ln2g, ln2b, Wo, W1, b1,
                                        W2, b2, lnfg, lnfb, Wout, bout, Wc1,
                                        bc1, Wc2, bc2, att, cnt, (float*)d_out);
}

// Round 14
// 109.275 us; speedup vs baseline: 1.3514x; 1.0538x over previous
//
#include <hip/hip_runtime.h>
#include <math.h>

#define NTOK 2048
#define NBF 266
#define MPAD 272
// zero region: ctx + ksum + gmax(4) + cnt(32) + pad(12)
#define ZWORDS4 138323u   // (2179072 + 34048 + 48) / 16

typedef unsigned short u16;
typedef __attribute__((ext_vector_type(8))) short short8;
typedef __attribute__((ext_vector_type(4))) float f32x4;

__device__ __forceinline__ float bf2f(u16 u) {
  unsigned int x = ((unsigned int)u) << 16;
  return __uint_as_float(x);
}
__device__ __forceinline__ u16 f2bf(float f) {
  unsigned int x = __float_as_uint(f);
  unsigned int r = x + 0x7FFFu + ((x >> 16) & 1u);
  return (u16)(r >> 16);
}
__device__ __forceinline__ float wredsum64(float v) {
  for (int o = 32; o > 0; o >>= 1) v += __shfl_xor(v, o);
  return v;
}
// 1024-thread block reductions (16 waves)
__device__ __forceinline__ float bsumK(float v, float* red) {
  for (int o = 32; o > 0; o >>= 1) v += __shfl_xor(v, o);
  __syncthreads();
  if ((threadIdx.x & 63) == 0) red[threadIdx.x >> 6] = v;
  __syncthreads();
  float s = 0;
#pragma unroll
  for (int i = 0; i < 16; ++i) s += red[i];
  return s;
}
__device__ __forceinline__ float bmaxK(float v, float* red) {
  for (int o = 32; o > 0; o >>= 1) v = fmaxf(v, __shfl_xor(v, o));
  __syncthreads();
  if ((threadIdx.x & 63) == 0) red[threadIdx.x >> 6] = v;
  __syncthreads();
  float s = -3e38f;
#pragma unroll
  for (int i = 0; i < 16; ++i) s = fmaxf(s, red[i]);
  return s;
}
#define INVF_C 0.4152410118609190f

// ---- prep v6: 128 thr / 8 tok / 4 cols; in-block LDS trig table ------------
__global__ __launch_bounds__(128) void k_prep(
    const int* __restrict__ ids, const float* __restrict__ tok_emb,
    const float* __restrict__ ln1g, const float* __restrict__ ln1b,
    const float* __restrict__ Wk, const float* __restrict__ Wv,
    u16* __restrict__ Kg, u16* __restrict__ Vg, u16* __restrict__ hng,
    float* __restrict__ diagK, float* __restrict__ x0,
    uint4* __restrict__ zbase) {
  int blk = blockIdx.x;            // 8 * 256 blocks
  int b = blk >> 8, nt = blk & 255;
  int n0 = nt * 8;
  int t = threadIdx.x;             // 0..127
  int w = t >> 6, lane = t & 63;
  __shared__ float hn[8][64];
  __shared__ float idm[8];
  __shared__ float2 sctab[256];    // [tok 0..7][freq 0..31]

  {
    unsigned int zi = (unsigned int)blk * 128u + (unsigned int)t;
    if (zi < ZWORDS4) zbase[zi] = make_uint4(0u, 0u, 0u, 0u);
  }
#pragma unroll
  for (int p = 0; p < 2; ++p) {
    int ee = t + p * 128;
    int n = n0 + (ee >> 5), i = ee & 31;
    float ang = (float)n * exp2f(-INVF_C * (float)i);
    sctab[ee] = make_float2(sinf(ang), cosf(ang));
  }
  __syncthreads();

  float g = ln1g[lane], bb = ln1b[lane];
#pragma unroll
  for (int j2 = 0; j2 < 4; ++j2) {
    int j = w * 4 + j2;
    int n = n0 + j;
    int id = ids[b * NTOK + n];
    float2 p = sctab[(j << 5) + (lane & 31)];
    float pv = (lane < 32) ? p.x : p.y;
    float xv = tok_emb[id * 64 + lane] + pv;
    float mu = wredsum64(xv) * 0.015625f;
    float dv = xv - mu;
    float var = wredsum64(dv * dv) * 0.015625f;
    float hv = dv * rsqrtf(var + 1e-5f) * g + bb;
    hn[j][lane] = hv;
    hng[((size_t)b * NTOK + n) * 64 + lane] = f2bf(hv);
    if (lane == 0) idm[j] = (id != 0) ? 1.f : 0.f;
    if (n == 0) x0[b * 64 + lane] = xv;
  }
  __syncthreads();

  float acc[8][4];
#pragma unroll
  for (int j = 0; j < 8; ++j)
#pragma unroll
    for (int i = 0; i < 4; ++i) acc[j][i] = 0.f;
  const float* wsrc = (t < 64) ? (Wk + t * 4) : (Wv + (t - 64) * 4);
  for (int d2 = 0; d2 < 64; ++d2) {
    float4 w0 = *reinterpret_cast<const float4*>(wsrc + d2 * 512);
#pragma unroll
    for (int j = 0; j < 8; ++j) {
      float hv = hn[j][d2];
      acc[j][0] += hv * w0.x; acc[j][1] += hv * w0.y;
      acc[j][2] += hv * w0.z; acc[j][3] += hv * w0.w;
    }
  }

  if (t < 64) {
    int hh = t >> 4, db = (t & 15) * 4;
    int i0 = (t & 15) * 2;
#pragma unroll
    for (int j = 0; j < 8; ++j) {
      int n = n0 + j;
      float2 t0 = sctab[(j << 5) + i0];
      float2 t1 = sctab[(j << 5) + i0 + 1];
      float s0 = t0.x, c0 = t0.y, s1 = t1.x, c1 = t1.y;
      float kr0 = acc[j][0] * c0 - acc[j][1] * s0;
      float kr1 = acc[j][1] * c0 + acc[j][0] * s0;
      float kr2 = acc[j][2] * c1 - acc[j][3] * s1;
      float kr3 = acc[j][3] * c1 + acc[j][2] * s1;
      float dq = kr0 * kr0 + kr1 * kr1 + kr2 * kr2 + kr3 * kr3;
      dq += __shfl_xor(dq, 1);
      dq += __shfl_xor(dq, 2);
      dq += __shfl_xor(dq, 4);
      dq += __shfl_xor(dq, 8);
      size_t hb = (size_t)(b * 4 + hh) * NTOK + n;
      if ((t & 15) == 0) diagK[hb] = dq * 0.0625f;
      ushort4 s;
      s.x = f2bf(kr0); s.y = f2bf(kr1); s.z = f2bf(kr2); s.w = f2bf(kr3);
      *reinterpret_cast<ushort4*>(Kg + hb * 64 + db) = s;
    }
  } else {
    int tv = t - 64;
    int hh = tv >> 4, db = (tv & 15) * 4;
#pragma unroll
    for (int j = 0; j < 8; ++j) {
      int n = n0 + j;
      float m = idm[j];
      ushort4 vv;
      vv.x = f2bf(acc[j][0] * m); vv.y = f2bf(acc[j][1] * m);
      vv.z = f2bf(acc[j][2] * m); vv.w = f2bf(acc[j][3] * m);
      *reinterpret_cast<ushort4*>(
          Vg + ((size_t)(b * 4 + hh) * NTOK + n) * 64 + db) = vv;
    }
  }
}

// ---- stage proj rows [m0, m0+rows) into swizzled bf16 LDS [rows][64] -------
__device__ __forceinline__ void stage_prj(const float* __restrict__ proj,
                                          u16* prjbf, int t, int m0, int rows) {
  for (int c = t; c < rows * 8; c += 256) {
    int r = c >> 3, k0 = (c & 7) * 8;
    int m = m0 + r;
    int e = (r * 64 + k0) ^ ((r & 7) << 3);
    uint4 pk;
    if (m < NBF) {
      const float4* ps = reinterpret_cast<const float4*>(proj + m * 64 + k0);
      float4 p0 = ps[0], p1 = ps[1];
      pk.x = (unsigned)f2bf(p0.x) | ((unsigned)f2bf(p0.y) << 16);
      pk.y = (unsigned)f2bf(p0.z) | ((unsigned)f2bf(p0.w) << 16);
      pk.z = (unsigned)f2bf(p1.x) | ((unsigned)f2bf(p1.y) << 16);
      pk.w = (unsigned)f2bf(p1.z) | ((unsigned)f2bf(p1.w) << 16);
    } else {
      pk.x = pk.y = pk.z = pk.w = 0u;
    }
    *reinterpret_cast<uint4*>(&prjbf[e]) = pk;
  }
}

// ---------------- global max over dash = dn * Kg @ proj^T (MFMA) ------------
__global__ __launch_bounds__(256) void k_max(
    const u16* __restrict__ Kg, const float* __restrict__ proj,
    unsigned int* __restrict__ gmax) {
  int bh = blockIdx.x, ns = blockIdx.y;
  int t = threadIdx.x, lane = t & 63, w = t >> 6;
  __shared__ __align__(16) u16 prjbf[MPAD * 64];
  __shared__ __align__(16) u16 kbf[64 * 64];
  __shared__ float red[4];
  stage_prj(proj, prjbf, t, 0, MPAD);
  float mv = -3e38f;
  int ko = (lane >> 4) * 8;
  for (int c4 = 0; c4 < 2; ++c4) {
    int nb = ns * 128 + c4 * 64;
    __syncthreads();
    for (int p = 0; p < 2; ++p) {
      int idx = t + p * 256;
      int n = idx >> 3, k0 = (idx & 7) * 8;
      uint4 src = *reinterpret_cast<const uint4*>(
          Kg + ((size_t)bh * NTOK + nb + n) * 64 + k0);
      *reinterpret_cast<uint4*>(&kbf[(n * 64 + k0) ^ ((n & 7) << 3)]) = src;
    }
    __syncthreads();
    int nl = w * 16 + (lane & 15);
    short8 a0 = *reinterpret_cast<const short8*>(&kbf[(nl * 64 + ko) ^ ((nl & 7) << 3)]);
    short8 a1 = *reinterpret_cast<const short8*>(&kbf[(nl * 64 + ko + 32) ^ ((nl & 7) << 3)]);
#pragma unroll
    for (int mt = 0; mt < 17; ++mt) {
      int m = mt * 16 + (lane & 15);
      short8 b0 = *reinterpret_cast<const short8*>(&prjbf[(m * 64 + ko) ^ ((m & 7) << 3)]);
      short8 b1 = *reinterpret_cast<const short8*>(&prjbf[(m * 64 + ko + 32) ^ ((m & 7) << 3)]);
      f32x4 d = {0.f, 0.f, 0.f, 0.f};
      d = __builtin_amdgcn_mfma_f32_16x16x32_bf16(a0, b0, d, 0, 0, 0);
      d = __builtin_amdgcn_mfma_f32_16x16x32_bf16(a1, b1, d, 0, 0, 0);
      if (m < NBF) {
        mv = fmaxf(mv, fmaxf(fmaxf(d[0], d[1]), fmaxf(d[2], d[3])));
      }
    }
  }
  mv *= 0.35355339059327373f;
  for (int o = 32; o > 0; o >>= 1) mv = fmaxf(mv, __shfl_xor(mv, o));
  __syncthreads();
  if (lane == 0) red[w] = mv;
  __syncthreads();
  if (t == 0) {
    float m2 = fmaxf(fmaxf(red[0], red[1]), fmaxf(red[2], red[3]));
    unsigned int b = __float_as_uint(m2);
    unsigned int u = (b & 0x80000000u) ? ~b : (b | 0x80000000u);
    atomicMax(gmax, u);
  }
}

// ---------------- ctx = kp^T @ Vg, ksum = sum_n kp (MFMA) -------------------
__global__ __launch_bounds__(256) void k_ctx(
    const u16* __restrict__ Kg, const u16* __restrict__ Vg,
    const float* __restrict__ diagK, const float* __restrict__ proj,
    const unsigned int* __restrict__ gmax,
    float* __restrict__ ctx, float* __restrict__ ksum) {
  int bh = blockIdx.x, ns = blockIdx.y, mz = blockIdx.z;
  int m0 = mz * 144;
  int nmt = mz ? 8 : 9;
  int t = threadIdx.x, lane = t & 63, w = t >> 6;
  __shared__ __align__(16) u16 prjbf[144 * 64];
  __shared__ __align__(16) u16 kpT[144 * 64];
  __shared__ __align__(16) u16 kbf[64 * 64];
  __shared__ __align__(16) u16 vbT[64 * 64];
  __shared__ float dg[64];
  __shared__ float ksl[144];
  stage_prj(proj, prjbf, t, m0, 144);
  if (t < 144) ksl[t] = 0.f;
  unsigned int u = *gmax;
  unsigned int bb = (u & 0x80000000u) ? (u & 0x7FFFFFFFu) : ~u;
  float mx = __uint_as_float(bb);
  const float dn = 0.35355339059327373f;
  const float ratio = 1.0f / sqrtf(266.0f);
  int ko = (lane >> 4) * 8;
  f32x4 acc[9];
  float ksacc[9];
#pragma unroll
  for (int i = 0; i < 9; ++i) { acc[i] = (f32x4){0.f, 0.f, 0.f, 0.f}; ksacc[i] = 0.f; }

  for (int c4 = 0; c4 < 4; ++c4) {
    int nb = ns * 256 + c4 * 64;
    for (int p = 0; p < 2; ++p) {
      int idx = t + p * 256;
      int n = idx >> 3, k0 = (idx & 7) * 8;
      uint4 src = *reinterpret_cast<const uint4*>(
          Kg + ((size_t)bh * NTOK + nb + n) * 64 + k0);
      *reinterpret_cast<uint4*>(&kbf[(n * 64 + k0) ^ ((n & 7) << 3)]) = src;
      uint4 vv = *reinterpret_cast<const uint4*>(
          Vg + ((size_t)bh * NTOK + nb + n) * 64 + k0);
      u16 pv[8];
      *reinterpret_cast<uint4*>(pv) = vv;
#pragma unroll
      for (int i = 0; i < 8; ++i) {
        int d = k0 + i;
        vbT[(d * 64 + n) ^ ((d & 7) << 3)] = pv[i];
      }
    }
    if (t < 64) dg[t] = diagK[(size_t)bh * NTOK + nb + t];
    __syncthreads();
    {
      int nl = w * 16 + (lane & 15);
      short8 a0 = *reinterpret_cast<const short8*>(&kbf[(nl * 64 + ko) ^ ((nl & 7) << 3)]);
      short8 a1 = *reinterpret_cast<const short8*>(&kbf[(nl * 64 + ko + 32) ^ ((nl & 7) << 3)]);
      float dgv[4];
#pragma unroll
      for (int r = 0; r < 4; ++r) dgv[r] = dg[w * 16 + (lane >> 4) * 4 + r];
      int n0 = w * 16 + (lane >> 4) * 4;
#pragma unroll
      for (int mt = 0; mt < 9; ++mt) {
        if (mt < nmt) {
          int lr = mt * 16 + (lane & 15);
          short8 b0 = *reinterpret_cast<const short8*>(&prjbf[(lr * 64 + ko) ^ ((lr & 7) << 3)]);
          short8 b1 = *reinterpret_cast<const short8*>(&prjbf[(lr * 64 + ko + 32) ^ ((lr & 7) << 3)]);
          f32x4 d = {0.f, 0.f, 0.f, 0.f};
          d = __builtin_amdgcn_mfma_f32_16x16x32_bf16(a0, b0, d, 0, 0, 0);
          d = __builtin_amdgcn_mfma_f32_16x16x32_bf16(a1, b1, d, 0, 0, 0);
          float kp0 = ratio * (expf(dn * d[0] - dgv[0] - mx) + 1e-4f);
          float kp1 = ratio * (expf(dn * d[1] - dgv[1] - mx) + 1e-4f);
          float kp2 = ratio * (expf(dn * d[2] - dgv[2] - mx) + 1e-4f);
          float kp3 = ratio * (expf(dn * d[3] - dgv[3] - mx) + 1e-4f);
          ushort4 pkk;
          pkk.x = f2bf(kp0); pkk.y = f2bf(kp1); pkk.z = f2bf(kp2); pkk.w = f2bf(kp3);
          *reinterpret_cast<ushort4*>(&kpT[(lr * 64 + n0) ^ ((lr & 7) << 3)]) = pkk;
          float ksp = kp0 + kp1 + kp2 + kp3;
          ksp += __shfl_xor(ksp, 16);
          ksp += __shfl_xor(ksp, 32);
          ksacc[mt] += ksp;
        }
      }
    }
    __syncthreads();
    {
      int dcol = w * 16 + (lane & 15);
      short8 vb0 = *reinterpret_cast<const short8*>(&vbT[(dcol * 64 + ko) ^ ((dcol & 7) << 3)]);
      short8 vb1 = *reinterpret_cast<const short8*>(&vbT[(dcol * 64 + ko + 32) ^ ((dcol & 7) << 3)]);
#pragma unroll
      for (int mt = 0; mt < 9; ++mt) {
        if (mt < nmt) {
          int lr = mt * 16 + (lane & 15);
          short8 a0 = *reinterpret_cast<const short8*>(&kpT[(lr * 64 + ko) ^ ((lr & 7) << 3)]);
          short8 a1 = *reinterpret_cast<const short8*>(&kpT[(lr * 64 + ko + 32) ^ ((lr & 7) << 3)]);
          acc[mt] = __builtin_amdgcn_mfma_f32_16x16x32_bf16(a0, vb0, acc[mt], 0, 0, 0);
          acc[mt] = __builtin_amdgcn_mfma_f32_16x16x32_bf16(a1, vb1, acc[mt], 0, 0, 0);
        }
      }
    }
    __syncthreads();
  }
  int dcol = w * 16 + (lane & 15);
#pragma unroll
  for (int mt = 0; mt < 9; ++mt) {
    if (mt < nmt) {
#pragma unroll
      for (int r = 0; r < 4; ++r) {
        int m = m0 + mt * 16 + (lane >> 4) * 4 + r;
        if (m < NBF)
          atomicAdd(&ctx[((size_t)bh * NBF + m) * 64 + dcol], acc[mt][r]);
      }
      if (lane < 16) atomicAdd(&ksl[mt * 16 + lane], ksacc[mt]);
    }
  }
  __syncthreads();
  if (t < 144 && m0 + t < NBF)
    atomicAdd(&ksum[(size_t)bh * NBF + m0 + t], ksl[t]);
}

// ---- attention row 0 per (b,head), 1024 threads; last block runs tail ------
__global__ __launch_bounds__(1024) void k_att(
    const int* __restrict__ ids,
    const float* __restrict__ ln1g, const float* __restrict__ ln1b,
    const float* __restrict__ Wq, const float* __restrict__ Wk,
    const float* __restrict__ Wv, const float* __restrict__ proj,
    const u16* __restrict__ hng,
    const float* __restrict__ ctx, const float* __restrict__ ksum,
    const float* __restrict__ x0,
    const float* __restrict__ ln2g, const float* __restrict__ ln2b,
    const float* __restrict__ Wo,
    const float* __restrict__ W1, const float* __restrict__ b1,
    const float* __restrict__ W2, const float* __restrict__ b2,
    const float* __restrict__ lnfg, const float* __restrict__ lnfb,
    const float* __restrict__ Wout, const float* __restrict__ bout,
    const float* __restrict__ Wc1, const float* __restrict__ bc1,
    const float* __restrict__ Wc2, const float* __restrict__ bc2,
    float* __restrict__ att, unsigned int* __restrict__ cnt,
    float* __restrict__ out) {
  int b = blockIdx.x, h = blockIdx.y;
  int t = threadIdx.x;              // 0..1023
  int lane = t & 63, wg = t >> 6;   // 16 waves
  __shared__ float hn1[64], qh[64], qpart[16][64], red[16], pol[16][64];
  __shared__ float buf[272];
  __shared__ float dots[2048];
  __shared__ float wkq[64], svec[64];
  __shared__ __align__(16) u16 vst[512 * 64];
  __shared__ int lastf;
  __shared__ float fo512[512], fx0[64], fy1[64], fhn2[64], fgact[256];
  __shared__ float fhfin[64], frep[64], fc1[32];
  const float dn = 0.35355339059327373f;
  const float ratio = 1.0f / sqrtf(266.0f);

  if (t < 64) {
    float xv = x0[b * 64 + t];
    float mu = wredsum64(xv) * 0.015625f;
    float dv = xv - mu;
    float var = wredsum64(dv * dv) * 0.015625f;
    hn1[t] = dv * rsqrtf(var + 1e-5f) * ln1g[t] + ln1b[t];
  }
  __syncthreads();
  {  // q: wg covers d-range wg*4..+3
    float p = 0;
#pragma unroll
    for (int dd = 0; dd < 4; ++dd)
      p += hn1[wg * 4 + dd] * Wq[(wg * 4 + dd) * 512 + h * 64 + lane];
    qpart[wg][lane] = p;
  }
  __syncthreads();
  if (t < 64) {
    float s = 0;
#pragma unroll
    for (int i = 0; i < 16; ++i) s += qpart[i][t];
    qh[t] = s;
  }
  __syncthreads();

  if (h < 4) {
    // ---- global (Performer) head ----
    int bh = b * 4 + h;
    float dq = 0;
#pragma unroll
    for (int d = 0; d < 64; ++d) dq += qh[d] * qh[d];
    dq *= 0.0625f;
    float lmax = -3e38f;
    {
      int m = t;
      if (m < NBF) {
        const float4* pp = reinterpret_cast<const float4*>(proj + m * 64);
        float s = 0;
#pragma unroll
        for (int q4 = 0; q4 < 16; ++q4) {
          float4 uu = pp[q4];
          s += qh[q4 * 4] * uu.x + qh[q4 * 4 + 1] * uu.y +
               qh[q4 * 4 + 2] * uu.z + qh[q4 * 4 + 3] * uu.w;
        }
        float dash = dn * s;
        buf[m] = dash;
        lmax = dash;
      }
    }
    float mxq = bmaxK(lmax, red);
    float part = 0;
    {
      int m = t;
      if (m < NBF) {
        float qp = ratio * (expf(buf[m] - dq - mxq) + 1e-4f);
        buf[m] = qp;
        part = qp * ksum[(size_t)bh * NBF + m];
      }
    }
    float den = bsumK(part, red);
    __syncthreads();
    {
      float s = 0;
      for (int m = wg; m < NBF; m += 16)
        s += buf[m] * ctx[((size_t)bh * NBF + m) * 64 + lane];
      pol[wg][lane] = s;
    }
    __syncthreads();
    if (t < 64) {
      float s = 0;
#pragma unroll
      for (int i = 0; i < 16; ++i) s += pol[i][t];
      att[b * 512 + h * 64 + t] = s / den;
    }
  } else {
    // ---- local head: dots = hn·(Wk_h q); ol = (Σ p·hn)·Wv_h / Σp ----
    int ch = h * 64;
    if (t < 64) {
      float s = 0;
#pragma unroll 8
      for (int j = 0; j < 64; ++j) s += Wk[t * 512 + ch + j] * qh[j];
      wkq[t] = s;
    }
    __syncthreads();
    const u16* hnb = hng + (size_t)b * NTOK * 64;
    float lmax = -3e38f;
#pragma unroll
    for (int i = 0; i < 2; ++i) {
      int n1 = t + i * 1024;
      const uint4* hr = reinterpret_cast<const uint4*>(hnb + (size_t)n1 * 64);
      float s = 0;
#pragma unroll
      for (int q8 = 0; q8 < 8; ++q8) {
        uint4 uu = hr[q8];
        u16 pv[8];
        *reinterpret_cast<uint4*>(pv) = uu;
#pragma unroll
        for (int k = 0; k < 8; ++k) s += wkq[q8 * 8 + k] * bf2f(pv[k]);
      }
      float dv = s * 0.125f;
      if (ids[b * NTOK + n1] == 0) dv = -1e9f;
      dots[n1] = dv;
      lmax = fmaxf(lmax, dv);
    }
    float mxl = bmaxK(lmax, red);
    float ps = 0;
#pragma unroll
    for (int i = 0; i < 2; ++i) {
      int n1 = t + i * 1024;
      float p = expf(dots[n1] - mxl);
      dots[n1] = p;
      ps += p;
    }
    float sden = bsumK(ps, red);
    // PV via LDS-staged chunks (512 rows = 64 KB, uint4 coalesced)
    float acc = 0;
    for (int c = 0; c < 4; ++c) {
      __syncthreads();
      const uint4* src = reinterpret_cast<const uint4*>(hnb + (size_t)(c * 512) * 64);
      uint4* dst = reinterpret_cast<uint4*>(vst);
#pragma unroll
      for (int i = 0; i < 4; ++i) dst[t + i * 1024] = src[t + i * 1024];
      __syncthreads();
      int r0 = wg * 32;
#pragma unroll 8
      for (int r = 0; r < 32; ++r)
        acc += dots[c * 512 + r0 + r] * bf2f(vst[(r0 + r) * 64 + lane]);
    }
    __syncthreads();
    pol[wg][lane] = acc;
    __syncthreads();
    if (t < 64) {
      float s = 0;
#pragma unroll
      for (int i = 0; i < 16; ++i) s += pol[i][t];
      svec[t] = s;
    }
    __syncthreads();
    {  // ol = (svec @ Wv_h) / sden ; wg covers dd-range wg*4..+3
      float p2 = 0;
#pragma unroll
      for (int dd = 0; dd < 4; ++dd)
        p2 += svec[wg * 4 + dd] * Wv[(wg * 4 + dd) * 512 + ch + lane];
      pol[wg][lane] = p2;
    }
    __syncthreads();
    if (t < 64) {
      float s = 0;
#pragma unroll
      for (int i = 0; i < 16; ++i) s += pol[i][t];
      att[b * 512 + h * 64 + t] = s / sden;
    }
  }

  // ---- completion count: last block for this b runs the tail ----
  __syncthreads();
  if (t == 0) {
    __threadfence();
    unsigned int prev = atomicAdd(&cnt[b], 1u);
    lastf = (prev == 7u) ? 1 : 0;
  }
  __syncthreads();
  if (!lastf) return;
  __threadfence();

  if (t < 512) fo512[t] = att[b * 512 + t];
  if (t < 64) fx0[t] = x0[b * 64 + t];
  __syncthreads();
  {  // Wo GEMV: wg covers c-range wg*32..+31
    float s = 0;
#pragma unroll 4
    for (int c = wg * 32; c < wg * 32 + 32; ++c) s += fo512[c] * Wo[c * 64 + lane];
    pol[wg][lane] = s;
  }
  __syncthreads();
  if (t < 64) {
    float s = 0;
#pragma unroll
    for (int i = 0; i < 16; ++i) s += pol[i][t];
    float yv = fx0[t] + s;
    fy1[t] = yv;
    float mu = wredsum64(yv) * 0.015625f;
    float dv = yv - mu;
    float var = wredsum64(dv * dv) * 0.015625f;
    fhn2[t] = dv * rsqrtf(var + 1e-5f) * ln2g[t] + ln2b[t];
  }
  __syncthreads();
  if (t < 256) {
    float s = b1[t];
#pragma unroll 4
    for (int d = 0; d < 64; ++d) s += fhn2[d] * W1[d * 256 + t];
    fgact[t] = 0.5f * s * (1.f + erff(s * 0.7071067811865475f));
  }
  __syncthreads();
  {  // W2 GEMV: wg covers j-range wg*16..+15
    float s = 0;
#pragma unroll 4
    for (int j = wg * 16; j < wg * 16 + 16; ++j) s += fgact[j] * W2[j * 64 + lane];
    pol[wg][lane] = s;
  }
  __syncthreads();
  if (t < 64) {
    float s = 0;
#pragma unroll
    for (int i = 0; i < 16; ++i) s += pol[i][t];
    float y2 = fx0[t] + b2[t] + s;
    float hm = 0.5f * (fy1[t] + y2);
    float mu = wredsum64(hm) * 0.015625f;
    float dv = hm - mu;
    float var = wredsum64(dv * dv) * 0.015625f;
    fhfin[t] = dv * rsqrtf(var + 1e-5f) * lnfg[t] + lnfb[t];
  }
  __syncthreads();
  {  // Wout GEMV: wg covers dd-range wg*4..+3
    float s = 0;
#pragma unroll
    for (int dd = 0; dd < 4; ++dd)
      s += fhfin[wg * 4 + dd] * Wout[(wg * 4 + dd) * 64 + lane];
    pol[wg][lane] = s;
  }
  __syncthreads();
  if (t < 64) {
    float s = bout[t];
#pragma unroll
    for (int i = 0; i < 16; ++i) s += pol[i][t];
    frep[t] = s;
    out[16 + b * 64 + t] = s;
  }
  __syncthreads();
  if (t < 32) {
    float s = bc1[t];
#pragma unroll 4
    for (int d = 0; d < 64; ++d) s += frep[d] * Wc1[d * 32 + t];
    fc1[t] = fmaxf(s, 0.f);
  }
  __syncthreads();
  if (t < 2) {
    float s = bc2[t];
#pragma unroll
    for (int jj = 0; jj < 32; ++jj) s += fc1[jj] * Wc2[jj * 2 + t];
    out[b * 2 + t] = s;
  }
}

extern "C" void kernel_launch(void* const* d_in, const int* in_sizes, int n_in,
                              void* d_out, int out_size, void* d_ws, size_t ws_size,
                              hipStream_t stream) {
  (void)in_sizes; (void)n_in; (void)out_size; (void)ws_size;
  const int* ids = (const int*)d_in[0];
  const float* tok = (const float*)d_in[1];
  const float* ln1g = (const float*)d_in[2];
  const float* ln1b = (const float*)d_in[3];
  const float* Wq = (const float*)d_in[4];
  const float* Wk = (const float*)d_in[5];
  const float* Wv = (const float*)d_in[6];
  const float* Wo = (const float*)d_in[7];
  const float* ln2g = (const float*)d_in[8];
  const float* ln2b = (const float*)d_in[9];
  const float* W1 = (const float*)d_in[10];
  const float* b1 = (const float*)d_in[11];
  const float* W2 = (const float*)d_in[12];
  const float* b2 = (const float*)d_in[13];
  const float* lnfg = (const float*)d_in[14];
  const float* lnfb = (const float*)d_in[15];
  const float* Wout = (const float*)d_in[16];
  const float* bout = (const float*)d_in[17];
  const float* Wc1 = (const float*)d_in[18];
  const float* bc1 = (const float*)d_in[19];
  const float* Wc2 = (const float*)d_in[20];
  const float* bc2 = (const float*)d_in[21];
  const float* proj = (const float*)d_in[22];

  uint8_t* w = (uint8_t*)d_ws;
  size_t off = 0;
  const size_t big = (size_t)8 * 4 * NTOK * 64 * 2;  // 8.39 MB each
  u16* Kg = (u16*)(w + off); off += big;
  u16* Vg = (u16*)(w + off); off += big;
  u16* hng = (u16*)(w + off); off += (size_t)8 * NTOK * 64 * 2;  // 2 MB
  float* diagK = (float*)(w + off); off += (size_t)8 * 4 * NTOK * 4;
  float* ctx = (float*)(w + off); off += (size_t)8 * 4 * NBF * 64 * 4;
  float* ksum = (float*)(w + off); off += (size_t)8 * 4 * NBF * 4;
  unsigned int* gmax = (unsigned int*)(w + off); off += 4;
  unsigned int* cnt = (unsigned int*)(w + off); off += 32;
  off += 12;  // pad so the zero region (ctx..cnt) is a whole uint4 count
  float* x0 = (float*)(w + off); off += 64 * 8 * 4;
  float* att = (float*)(w + off); off += (size_t)8 * 512 * 4;

  k_prep<<<8 * 256, 128, 0, stream>>>(ids, tok, ln1g, ln1b, Wk, Wv, Kg, Vg, hng,
                                      diagK, x0, (uint4*)ctx);
  k_max<<<dim3(32, 16), 256, 0, stream>>>(Kg, proj, gmax);
  k_ctx<<<dim3(32, 8, 2), 256, 0, stream>>>(Kg, Vg, diagK, proj, gmax, ctx, ksum);
  k_att<<<dim3(8, 8), 1024, 0, stream>>>(ids, ln1g, ln1b, Wq, Wk, Wv, proj, hng,
                                         ctx, ksum, x0, ln2g, ln2b, Wo, W1, b1,
                                         W2, b2, lnfg, lnfb, Wout, bout, Wc1,
                                         bc1, Wc2, bc2, att, cnt, (float*)d_out);
}